// Round 8
// baseline (237.068 us; speedup 1.0000x reference)
//
#include <hip/hip_runtime.h>

// ---------------------------------------------------------------------------
// LatentMixtureAllRNNAgent: per-agent fc1 -> GRU cell -> fc2 on MI355X.
// Round 8: k2 rebuilt as 8192 x 1-wave (64-thread) blocks, ZERO LDS, 32x32
// output slice per wave, A-fragments (x,h bf16) streamed from ws via L1/L2,
// rowsums via MFMA-with-ones (exact f32, lands in the acc row mapping).
// Residency law from rounds 4-7: waves/SIMD = 512/(VGPR+AGPR); LDS rounds up
// to 64KB per block. 1-wave blocks + no LDS + <=170 regs -> ~12 waves/CU.
// Numerics: same bf16 inputs/weights as rounds 2-7 (absmax 1.0); only f32
// summation-order changes (MFMA-tree rowsum; NG accumulated into T via C-in).
// ---------------------------------------------------------------------------

typedef __attribute__((ext_vector_type(4))) float f32x4;
typedef __attribute__((ext_vector_type(8))) short s8;     // 8 bf16 (4 VGPRs)
typedef __attribute__((ext_vector_type(4))) unsigned short us4;
typedef __attribute__((ext_vector_type(8))) unsigned short us8;

#define QSIZE   983040      /* 32768*30 */
#define W1H_OFF 0
#define W1L_OFF 524288
#define WIH_OFF 1048576
#define WHH_OFF 2621440
#define W2T_OFF 4194304
#define XB_OFF  4259840                 /* X bf16: 32768*256 */
#define HB_OFF  12648448                /* h_in bf16: 32768*256 */
#define WS_NEED_NEW 42074112ull        /* (HB_OFF + 8388608)*2 bytes */
#define WS_NEED_OLD 25296896ull        /* (XB_OFF + 8388608)*2 bytes */

static __device__ __forceinline__ unsigned short f2bf(float f) {
  union { float f; unsigned u; } v; v.f = f;
  unsigned r = v.u + 0x7FFFu + ((v.u >> 16) & 1u);   // RNE
  return (unsigned short)(r >> 16);
}
static __device__ __forceinline__ float bf2f(unsigned short u) {
  union { unsigned u; float f; } v; v.u = ((unsigned)u) << 16;
  return v.f;
}
static __device__ __forceinline__ float sigm(float x) {
  return 1.0f / (1.0f + __expf(-x));
}
static __device__ __forceinline__ float tanh_(float x) {
  return 1.0f - 2.0f / (__expf(2.0f * x) + 1.0f);
}

// ------------- prep: f32 [a][k][n] -> bf16 [a][n][k] planes in ws -----------
__global__ void prep_weights(const float* __restrict__ fc1w,
                             const float* __restrict__ rihw,
                             const float* __restrict__ rhhw,
                             const float* __restrict__ fc2w,
                             unsigned short* __restrict__ ws) {
  int q = blockIdx.x * 256 + threadIdx.x;
  if (q < 131072) {                         // fc1: hi + lo planes
    int a = q >> 14, rem = q & 16383, k4 = rem >> 8, n = rem & 255;
    const float* s = fc1w + a * 65536 + (k4 * 4) * 256 + n;
    float v0 = s[0], v1 = s[256], v2 = s[512], v3 = s[768];
    us4 hi = { f2bf(v0), f2bf(v1), f2bf(v2), f2bf(v3) };
    us4 lo = { f2bf(v0 - bf2f(hi[0])), f2bf(v1 - bf2f(hi[1])),
               f2bf(v2 - bf2f(hi[2])), f2bf(v3 - bf2f(hi[3])) };
    int o = ((a * 256 + n) << 8) + k4 * 4;
    *(us4*)(ws + W1H_OFF + o) = hi;
    *(us4*)(ws + W1L_OFF + o) = lo;
  } else if (q < 524288) {                  // rnn_ih, centered (w - 0.5)
    int t = q - 131072;
    int a = t / 49152, rem = t % 49152, k4 = rem / 768, n = rem % 768;
    const float* s = rihw + a * 196608 + (k4 * 4) * 768 + n;
    us4 v = { f2bf(s[0] - 0.5f), f2bf(s[768] - 0.5f),
              f2bf(s[1536] - 0.5f), f2bf(s[2304] - 0.5f) };
    *(us4*)(ws + WIH_OFF + ((a * 768 + n) << 8) + k4 * 4) = v;
  } else if (q < 917504) {                  // rnn_hh, centered
    int t = q - 524288;
    int a = t / 49152, rem = t % 49152, k4 = rem / 768, n = rem % 768;
    const float* s = rhhw + a * 196608 + (k4 * 4) * 768 + n;
    us4 v = { f2bf(s[0] - 0.5f), f2bf(s[768] - 0.5f),
              f2bf(s[1536] - 0.5f), f2bf(s[2304] - 0.5f) };
    *(us4*)(ws + WHH_OFF + ((a * 768 + n) << 8) + k4 * 4) = v;
  } else if (q < 933888) {                  // fc2: plain, pad 30->32
    int t = q - 917504;
    int a = t >> 11, rem = t & 2047, k4 = rem >> 5, n = rem & 31;
    us4 v = { 0, 0, 0, 0 };
    if (n < 30) {
      const float* s = fc2w + a * 7680 + (k4 * 4) * 30 + n;
      v = (us4){ f2bf(s[0]), f2bf(s[30]), f2bf(s[60]), f2bf(s[90]) };
    }
    *(us4*)(ws + W2T_OFF + ((a * 32 + n) << 8) + k4 * 4) = v;
  }
}

// ------- stage 32x256 f32 tile -> split bf16 (hi p0, lo p1), 256 thr --------
static __device__ __forceinline__ void stage_split(unsigned short* p0,
                                                   unsigned short* p1,
                                                   const float* __restrict__ src,
                                                   int rowbase, int a, int tid) {
#pragma unroll
  for (int k = 0; k < 8; ++k) {
    int j = tid + k * 256;
    int r = j >> 6;
    int c4 = (j & 63) << 2;
    const float* p = src + ((((rowbase + r) << 3) + a) << 8) + c4;
    float4 v = *(const float4*)p;
    us4 hi = { f2bf(v.x), f2bf(v.y), f2bf(v.z), f2bf(v.w) };
    us4 lo = { f2bf(v.x - bf2f(hi[0])), f2bf(v.y - bf2f(hi[1])),
               f2bf(v.z - bf2f(hi[2])), f2bf(v.w - bf2f(hi[3])) };
    int idx = ((r << 8) + c4) ^ ((r & 7) << 3);   // XOR swizzle (16B blocks)
    *(us4*)(p0 + idx) = hi;
    *(us4*)(p1 + idx) = lo;
  }
}

// ------------- stage 32x256 f32 tile -> single bf16 plane, 256 thr ----------
static __device__ __forceinline__ void stage_single(unsigned short* p,
                                                    const float* __restrict__ src,
                                                    int rowbase, int a, int tid) {
#pragma unroll
  for (int k = 0; k < 8; ++k) {
    int j = tid + k * 256;
    int r = j >> 6;
    int c4 = (j & 63) << 2;
    const float* sp = src + ((((rowbase + r) << 3) + a) << 8) + c4;
    float4 v = *(const float4*)sp;
    us4 hi = { f2bf(v.x), f2bf(v.y), f2bf(v.z), f2bf(v.w) };
    int idx = ((r << 8) + c4) ^ ((r & 7) << 3);
    *(us4*)(p + idx) = hi;
  }
}

// ---- 32x64 tile GEMM over K=256: acc[2][4] += A_lds @ Wt^T -----------------
static __device__ __forceinline__ void mma64(const unsigned short* lds,
                                             const unsigned short* __restrict__ wt,
                                             int n0, int l16, int l4,
                                             f32x4 (&acc)[2][4]) {
#pragma unroll
  for (int ks = 0; ks < 8; ++ks) {
    s8 af[2], bw[4];
#pragma unroll
    for (int mt = 0; mt < 2; ++mt) {
      int row = mt * 16 + l16;
      int idx = ((row << 8) + ks * 32 + 8 * l4) ^ ((row & 7) << 3);
      af[mt] = *(const s8*)(lds + idx);
    }
#pragma unroll
    for (int nt = 0; nt < 4; ++nt) {
      bw[nt] = *(const s8*)(wt + ((n0 + nt * 16 + l16) << 8) + ks * 32 + 8 * l4);
    }
#pragma unroll
    for (int mt = 0; mt < 2; ++mt)
#pragma unroll
      for (int nt = 0; nt < 4; ++nt)
        acc[mt][nt] = __builtin_amdgcn_mfma_f32_16x16x32_bf16(
            af[mt], bw[nt], acc[mt][nt], 0, 0, 0);
  }
}

// ========================== K1: fc1 -> X bf16 (ws) [+ h_in bf16] ===========
__global__ __launch_bounds__(256, 2) void k1_fc1(
    const float* __restrict__ inp, const float* __restrict__ hin,
    const float* __restrict__ b1, unsigned short* __restrict__ ws, int whb) {
  __shared__ __align__(16) unsigned short P0[32 * 256];
  __shared__ __align__(16) unsigned short P1[32 * 256];
  const int tid = threadIdx.x;
  const int a = blockIdx.x & 7;
  const int rowbase = (blockIdx.x >> 3) * 32;
  const int lane = tid & 63, w = tid >> 6;
  const int l16 = lane & 15, l4 = lane >> 4;
  const int n0 = w * 64;

  stage_split(P0, P1, inp, rowbase, a, tid);

  if (whb) {      // stage h_in -> bf16 in ws (straight copy, no LDS)
#pragma unroll
    for (int k = 0; k < 8; ++k) {
      int j = tid + k * 256;
      int r = j >> 6;
      int c4 = (j & 63) << 2;
      int flat = ((rowbase + r) << 3) + a;
      float4 v = *(const float4*)(hin + (flat << 8) + c4);
      us4 u = { f2bf(v.x), f2bf(v.y), f2bf(v.z), f2bf(v.w) };
      *(us4*)(ws + HB_OFF + (flat << 8) + c4) = u;
    }
  }
  __syncthreads();

  f32x4 XA[2][4];
#pragma unroll
  for (int mt = 0; mt < 2; ++mt)
#pragma unroll
    for (int nt = 0; nt < 4; ++nt) XA[mt][nt] = (f32x4){0.f, 0.f, 0.f, 0.f};
  mma64(P0, ws + W1H_OFF + a * 65536, n0, l16, l4, XA);
  mma64(P1, ws + W1H_OFF + a * 65536, n0, l16, l4, XA);
  mma64(P0, ws + W1L_OFF + a * 65536, n0, l16, l4, XA);

#pragma unroll
  for (int nt = 0; nt < 4; ++nt) {
    int col = n0 + nt * 16 + l16;
    float bb = b1[a * 256 + col];
#pragma unroll
    for (int mt = 0; mt < 2; ++mt)
#pragma unroll
      for (int r = 0; r < 4; ++r) {
        float v = fmaxf(XA[mt][nt][r] + bb, 0.f);
        int row = mt * 16 + l4 * 4 + r;
        int flat = ((rowbase + row) << 3) + a;
        ws[XB_OFF + (flat << 8) + col] = f2bf(v);
      }
  }
}

// ============ K2 (new): 1-wave blocks, 32x32 slice, zero LDS ================
__global__ __launch_bounds__(64, 3) void k2_gates_nw(
    const float* __restrict__ bih, const float* __restrict__ bhh,
    const unsigned short* __restrict__ ws, float* __restrict__ out) {
  const int tid = threadIdx.x;           // 0..63
  const int bid = blockIdx.x;
  const int a   = bid & 7;               // agent == XCD
  const int t   = bid >> 3;              // 0..1023
  const int cs  = t >> 7;                // col-slice 0..7 (32 cols)
  const int rt  = t & 127;               // row-tile   (32 rows)
  const int rowbase = rt * 32;
  const int n0  = cs * 32;
  const int l16 = tid & 15, l4 = tid >> 4;

  const unsigned short* WihA = ws + WIH_OFF + a * 196608;
  const unsigned short* WhhA = ws + WHH_OFF + a * 196608;

  // per-lane A-fragment bases: rows (rowbase + mt*16 + l16), k offset 8*l4
  const unsigned short* ax0 = ws + XB_OFF + ((((rowbase + l16)      << 3) + a) << 8) + 8 * l4;
  const unsigned short* ax1 = ws + XB_OFF + ((((rowbase + 16 + l16) << 3) + a) << 8) + 8 * l4;
  const unsigned short* ah0 = ws + HB_OFF + ((((rowbase + l16)      << 3) + a) << 8) + 8 * l4;
  const unsigned short* ah1 = ws + HB_OFF + ((((rowbase + 16 + l16) << 3) + a) << 8) + 8 * l4;

  s8 ones;
#pragma unroll
  for (int i = 0; i < 8; ++i) ones[i] = (short)0x3F80;   // bf16 1.0

  f32x4 R[2][2], T[2][2], SX[2], SH[2];
#pragma unroll
  for (int mt = 0; mt < 2; ++mt) {
    SX[mt] = (f32x4){0.f, 0.f, 0.f, 0.f};
    SH[mt] = (f32x4){0.f, 0.f, 0.f, 0.f};
#pragma unroll
    for (int nt = 0; nt < 2; ++nt) {
      R[mt][nt] = (f32x4){0.f, 0.f, 0.f, 0.f};
      T[mt][nt] = (f32x4){0.f, 0.f, 0.f, 0.f};
    }
  }

  // ---- phase 1: resetgate accs + exact rowsums (MFMA with ones-B) ----
#pragma unroll
  for (int ks = 0; ks < 8; ++ks) {
    s8 ax[2] = { *(const s8*)(ax0 + ks * 32), *(const s8*)(ax1 + ks * 32) };
    s8 ah[2] = { *(const s8*)(ah0 + ks * 32), *(const s8*)(ah1 + ks * 32) };
    s8 bx[2], bh[2];
#pragma unroll
    for (int nt = 0; nt < 2; ++nt) {
      int wrow = n0 + nt * 16 + l16;
      bx[nt] = *(const s8*)(WihA + (wrow << 8) + ks * 32 + 8 * l4);
      bh[nt] = *(const s8*)(WhhA + (wrow << 8) + ks * 32 + 8 * l4);
    }
#pragma unroll
    for (int mt = 0; mt < 2; ++mt) {
      SX[mt] = __builtin_amdgcn_mfma_f32_16x16x32_bf16(ax[mt], ones, SX[mt], 0, 0, 0);
      SH[mt] = __builtin_amdgcn_mfma_f32_16x16x32_bf16(ah[mt], ones, SH[mt], 0, 0, 0);
#pragma unroll
      for (int nt = 0; nt < 2; ++nt) {
        R[mt][nt] = __builtin_amdgcn_mfma_f32_16x16x32_bf16(ax[mt], bx[nt], R[mt][nt], 0, 0, 0);
        R[mt][nt] = __builtin_amdgcn_mfma_f32_16x16x32_bf16(ah[mt], bh[nt], R[mt][nt], 0, 0, 0);
      }
    }
  }
  // r = sigmoid(acc + 0.5*(rsx+rsh) + biases)   [SX/SH rows match acc rows]
#pragma unroll
  for (int nt = 0; nt < 2; ++nt) {
    int col = n0 + nt * 16 + l16;
    float bb = bih[a * 768 + col] + bhh[a * 768 + col];
#pragma unroll
    for (int mt = 0; mt < 2; ++mt)
#pragma unroll
      for (int r = 0; r < 4; ++r)
        R[mt][nt][r] = sigm(R[mt][nt][r] + 0.5f * (SX[mt][r] + SH[mt][r]) + bb);
  }

  // ---- phase 2: T = h @ Whh_n ----
#pragma unroll
  for (int ks = 0; ks < 8; ++ks) {
    s8 ah[2] = { *(const s8*)(ah0 + ks * 32), *(const s8*)(ah1 + ks * 32) };
    s8 bn[2];
#pragma unroll
    for (int nt = 0; nt < 2; ++nt)
      bn[nt] = *(const s8*)(WhhA + ((512 + n0 + nt * 16 + l16) << 8) + ks * 32 + 8 * l4);
#pragma unroll
    for (int mt = 0; mt < 2; ++mt)
#pragma unroll
      for (int nt = 0; nt < 2; ++nt)
        T[mt][nt] = __builtin_amdgcn_mfma_f32_16x16x32_bf16(ah[mt], bn[nt], T[mt][nt], 0, 0, 0);
  }
  // T = r * (T + 0.5*rsh + bhh_n)
#pragma unroll
  for (int nt = 0; nt < 2; ++nt) {
    int col = n0 + nt * 16 + l16;
    float bb = bhh[a * 768 + 512 + col];
#pragma unroll
    for (int mt = 0; mt < 2; ++mt)
#pragma unroll
      for (int r = 0; r < 4; ++r)
        T[mt][nt][r] = R[mt][nt][r] * (T[mt][nt][r] + 0.5f * SH[mt][r] + bb);
  }

  // ---- phase 3: newgate — accumulate x @ Wih_n INTO T via MFMA C-in ----
#pragma unroll
  for (int ks = 0; ks < 8; ++ks) {
    s8 ax[2] = { *(const s8*)(ax0 + ks * 32), *(const s8*)(ax1 + ks * 32) };
    s8 bn[2];
#pragma unroll
    for (int nt = 0; nt < 2; ++nt)
      bn[nt] = *(const s8*)(WihA + ((512 + n0 + nt * 16 + l16) << 8) + ks * 32 + 8 * l4);
#pragma unroll
    for (int mt = 0; mt < 2; ++mt)
#pragma unroll
      for (int nt = 0; nt < 2; ++nt)
        T[mt][nt] = __builtin_amdgcn_mfma_f32_16x16x32_bf16(ax[mt], bn[nt], T[mt][nt], 0, 0, 0);
  }
  // T = tanh(T + 0.5*rsx + bih_n)
#pragma unroll
  for (int nt = 0; nt < 2; ++nt) {
    int col = n0 + nt * 16 + l16;
    float bb = bih[a * 768 + 512 + col];
#pragma unroll
    for (int mt = 0; mt < 2; ++mt)
#pragma unroll
      for (int r = 0; r < 4; ++r)
        T[mt][nt][r] = tanh_(T[mt][nt][r] + 0.5f * SX[mt][r] + bb);
  }

  // ---- phase 4: inputgate (reuse R), combine, store h ----
#pragma unroll
  for (int mt = 0; mt < 2; ++mt)
#pragma unroll
    for (int nt = 0; nt < 2; ++nt) R[mt][nt] = (f32x4){0.f, 0.f, 0.f, 0.f};
#pragma unroll
  for (int ks = 0; ks < 8; ++ks) {
    s8 ax[2] = { *(const s8*)(ax0 + ks * 32), *(const s8*)(ax1 + ks * 32) };
    s8 ah[2] = { *(const s8*)(ah0 + ks * 32), *(const s8*)(ah1 + ks * 32) };
    s8 bx[2], bh[2];
#pragma unroll
    for (int nt = 0; nt < 2; ++nt) {
      int wrow = 256 + n0 + nt * 16 + l16;
      bx[nt] = *(const s8*)(WihA + (wrow << 8) + ks * 32 + 8 * l4);
      bh[nt] = *(const s8*)(WhhA + (wrow << 8) + ks * 32 + 8 * l4);
    }
#pragma unroll
    for (int mt = 0; mt < 2; ++mt)
#pragma unroll
      for (int nt = 0; nt < 2; ++nt) {
        R[mt][nt] = __builtin_amdgcn_mfma_f32_16x16x32_bf16(ax[mt], bx[nt], R[mt][nt], 0, 0, 0);
        R[mt][nt] = __builtin_amdgcn_mfma_f32_16x16x32_bf16(ah[mt], bh[nt], R[mt][nt], 0, 0, 0);
      }
  }
#pragma unroll
  for (int nt = 0; nt < 2; ++nt) {
    int col = n0 + nt * 16 + l16;
    float bb = bih[a * 768 + 256 + col] + bhh[a * 768 + 256 + col];
#pragma unroll
    for (int mt = 0; mt < 2; ++mt)
#pragma unroll
      for (int r = 0; r < 4; ++r) {
        int row = mt * 16 + l4 * 4 + r;
        int flat = ((rowbase + row) << 3) + a;
        float ig = sigm(R[mt][nt][r] + 0.5f * (SX[mt][r] + SH[mt][r]) + bb);
        float hv = bf2f(ws[HB_OFF + (flat << 8) + col]);
        float ng = T[mt][nt][r];
        out[QSIZE + (flat << 8) + col] = ng + ig * (hv - ng);
      }
  }
}

// ============ K2 (old, round-7 wide): fallback when ws < 42 MB ==============
__global__ __launch_bounds__(256, 1) void k2_gates(
    const float* __restrict__ hin, const float* __restrict__ bih,
    const float* __restrict__ bhh, const unsigned short* __restrict__ ws,
    float* __restrict__ out) {
  __shared__ __align__(16) unsigned short P0[32 * 256];
  __shared__ __align__(16) unsigned short P1[32 * 256];
  __shared__ float RSXP[8][32], RSHP[8][32];
  __shared__ float RSX[32], RSH[32];

  const int tid = threadIdx.x;
  const int a = blockIdx.x & 7;
  const int rowbase = (blockIdx.x >> 3) * 32;
  const int lane = tid & 63, w = tid >> 6;
  const int l16 = lane & 15, l4 = lane >> 4;
  const int n0 = w * 64;

#pragma unroll
  for (int k = 0; k < 4; ++k) {
    int j = tid + k * 256;
    int r = j >> 5;
    int c = (j & 31) << 3;
    us8 v = *(const us8*)(ws + XB_OFF + ((((rowbase + r) << 3) + a) << 8) + c);
    int idx = ((r << 8) + c) ^ ((r & 7) << 3);
    *(us8*)(P0 + idx) = v;
  }
  stage_single(P1, hin, rowbase, a, tid);
  __syncthreads();

  {
    int row = tid >> 3, qd = tid & 7;
    float sx = 0.f, sh = 0.f;
#pragma unroll
    for (int i = 0; i < 8; ++i) {
      int c = qd * 32 + i * 4;
      int idx = ((row << 8) + c) ^ ((row & 7) << 3);
      us4 vx = *(const us4*)(P0 + idx);
      us4 vh = *(const us4*)(P1 + idx);
      sx += bf2f(vx[0]) + bf2f(vx[1]) + bf2f(vx[2]) + bf2f(vx[3]);
      sh += bf2f(vh[0]) + bf2f(vh[1]) + bf2f(vh[2]) + bf2f(vh[3]);
    }
    RSXP[qd][row] = sx; RSHP[qd][row] = sh;
  }
  __syncthreads();
  if (tid < 32) {
    float sx = 0.f, sh = 0.f;
#pragma unroll
    for (int qd = 0; qd < 8; ++qd) { sx += RSXP[qd][tid]; sh += RSHP[qd][tid]; }
    RSX[tid] = sx; RSH[tid] = sh;
  }
  __syncthreads();

  const unsigned short* WihA = ws + WIH_OFF + a * 768 * 256;
  const unsigned short* WhhA = ws + WHH_OFF + a * 768 * 256;

  f32x4 R[2][4], T[2][4];
#pragma unroll
  for (int mt = 0; mt < 2; ++mt)
#pragma unroll
    for (int nt = 0; nt < 4; ++nt) R[mt][nt] = (f32x4){0.f, 0.f, 0.f, 0.f};
  mma64(P0, WihA, n0, l16, l4, R);
  mma64(P1, WhhA, n0, l16, l4, R);
#pragma unroll
  for (int nt = 0; nt < 4; ++nt) {
    int col = n0 + nt * 16 + l16;
    float bb = bih[a * 768 + col] + bhh[a * 768 + col];
#pragma unroll
    for (int mt = 0; mt < 2; ++mt)
#pragma unroll
      for (int r = 0; r < 4; ++r) {
        int row = mt * 16 + l4 * 4 + r;
        R[mt][nt][r] = sigm(R[mt][nt][r] + 0.5f * (RSX[row] + RSH[row]) + bb);
      }
  }
#pragma unroll
  for (int mt = 0; mt < 2; ++mt)
#pragma unroll
    for (int nt = 0; nt < 4; ++nt) T[mt][nt] = (f32x4){0.f, 0.f, 0.f, 0.f};
  mma64(P1, WhhA + 512 * 256, n0, l16, l4, T);
#pragma unroll
  for (int nt = 0; nt < 4; ++nt) {
    int col = n0 + nt * 16 + l16;
    float bb = bhh[a * 768 + 512 + col];
#pragma unroll
    for (int mt = 0; mt < 2; ++mt)
#pragma unroll
      for (int r = 0; r < 4; ++r) {
        int row = mt * 16 + l4 * 4 + r;
        T[mt][nt][r] = R[mt][nt][r] * (T[mt][nt][r] + 0.5f * RSH[row] + bb);
      }
  }
  mma64(P0, WihA + 512 * 256, n0, l16, l4, T);
#pragma unroll
  for (int nt = 0; nt < 4; ++nt) {
    int col = n0 + nt * 16 + l16;
    float bb = bih[a * 768 + 512 + col];
#pragma unroll
    for (int mt = 0; mt < 2; ++mt)
#pragma unroll
      for (int r = 0; r < 4; ++r) {
        int row = mt * 16 + l4 * 4 + r;
        T[mt][nt][r] = tanh_(T[mt][nt][r] + 0.5f * RSX[row] + bb);
      }
  }
#pragma unroll
  for (int mt = 0; mt < 2; ++mt)
#pragma unroll
    for (int nt = 0; nt < 4; ++nt) R[mt][nt] = (f32x4){0.f, 0.f, 0.f, 0.f};
  mma64(P0, WihA + 256 * 256, n0, l16, l4, R);
  mma64(P1, WhhA + 256 * 256, n0, l16, l4, R);
#pragma unroll
  for (int nt = 0; nt < 4; ++nt) {
    int col = n0 + nt * 16 + l16;
    float bb = bih[a * 768 + 256 + col] + bhh[a * 768 + 256 + col];
#pragma unroll
    for (int mt = 0; mt < 2; ++mt)
#pragma unroll
      for (int r = 0; r < 4; ++r) {
        int row = mt * 16 + l4 * 4 + r;
        float ig = sigm(R[mt][nt][r] + 0.5f * (RSX[row] + RSH[row]) + bb);
        float hv = bf2f(P1[((row << 8) + col) ^ ((row & 7) << 3)]);
        float ng = T[mt][nt][r];
        out[QSIZE + ((((rowbase + row) << 3) + a) << 8) + col]
            = ng + ig * (hv - ng);
      }
  }
}

// ========================== K3: fc2 -> q (out) ==============================
__global__ __launch_bounds__(128) void k3_fc2(
    const float* __restrict__ b2, const unsigned short* __restrict__ ws,
    float* __restrict__ out) {
  __shared__ __align__(16) unsigned short HB[32 * 256];
  const int tid = threadIdx.x;
  const int a = blockIdx.x & 7;
  const int rowbase = (blockIdx.x >> 3) * 32;
  const int lane = tid & 63, w = tid >> 6;
  const int l16 = lane & 15, l4 = lane >> 4;

#pragma unroll
  for (int k = 0; k < 16; ++k) {
    int j = tid + k * 128;
    int r = j >> 6;
    int c4 = (j & 63) << 2;
    const float* sp = out + QSIZE + ((((rowbase + r) << 3) + a) << 8) + c4;
    float4 v = *(const float4*)sp;
    us4 hi = { f2bf(v.x), f2bf(v.y), f2bf(v.z), f2bf(v.w) };
    int idx = ((r << 8) + c4) ^ ((r & 7) << 3);
    *(us4*)(HB + idx) = hi;
  }
  __syncthreads();

  f32x4 qa[2];
  qa[0] = (f32x4){0.f, 0.f, 0.f, 0.f};
  qa[1] = (f32x4){0.f, 0.f, 0.f, 0.f};
#pragma unroll
  for (int ks = 0; ks < 8; ++ks) {
    int row = w * 16 + l16;
    int idx = ((row << 8) + ks * 32 + 8 * l4) ^ ((row & 7) << 3);
    s8 af = *(const s8*)(HB + idx);
#pragma unroll
    for (int nt = 0; nt < 2; ++nt) {
      s8 bw = *(const s8*)(ws + W2T_OFF + ((a * 32 + nt * 16 + l16) << 8) + ks * 32 + 8 * l4);
      qa[nt] = __builtin_amdgcn_mfma_f32_16x16x32_bf16(af, bw, qa[nt], 0, 0, 0);
    }
  }
#pragma unroll
  for (int nt = 0; nt < 2; ++nt) {
    int col = nt * 16 + l16;
    if (col < 30) {
      float bb = b2[a * 30 + col];
#pragma unroll
      for (int r = 0; r < 4; ++r) {
        int row = w * 16 + l4 * 4 + r;
        out[(((rowbase + row) << 3) + a) * 30 + col] = fmaxf(qa[nt][r] + bb, 0.f);
      }
    }
  }
}

extern "C" void kernel_launch(void* const* d_in, const int* in_sizes, int n_in,
                              void* d_out, int out_size, void* d_ws, size_t ws_size,
                              hipStream_t stream) {
  const float* inputs = (const float*)d_in[0];
  const float* hidden = (const float*)d_in[1];
  const float* fc1w   = (const float*)d_in[2];
  const float* fc1b   = (const float*)d_in[3];
  const float* rihw   = (const float*)d_in[4];
  const float* rihb   = (const float*)d_in[5];
  const float* rhhw   = (const float*)d_in[6];
  const float* rhhb   = (const float*)d_in[7];
  const float* fc2w   = (const float*)d_in[8];
  const float* fc2b   = (const float*)d_in[9];
  unsigned short* ws  = (unsigned short*)d_ws;
  float* out          = (float*)d_out;

  hipLaunchKernelGGL(prep_weights, dim3(3648), dim3(256), 0, stream,
                     fc1w, rihw, rhhw, fc2w, ws);

  if (ws_size >= WS_NEED_NEW) {
    hipLaunchKernelGGL(k1_fc1, dim3(1024), dim3(256), 0, stream,
                       inputs, hidden, fc1b, ws, 1);
    hipLaunchKernelGGL(k2_gates_nw, dim3(8192), dim3(64), 0, stream,
                       rihb, rhhb, ws, out);
    hipLaunchKernelGGL(k3_fc2, dim3(1024), dim3(128), 0, stream, fc2b, ws, out);
  } else {
    // round-7 proven path (181 us)
    hipLaunchKernelGGL(k1_fc1, dim3(1024), dim3(256), 0, stream,
                       inputs, hidden, fc1b, ws, 0);
    hipLaunchKernelGGL(k2_gates, dim3(1024), dim3(256), 0, stream,
                       hidden, rihb, rhhb, ws, out);
    hipLaunchKernelGGL(k3_fc2, dim3(1024), dim3(128), 0, stream, fc2b, ws, out);
  }
}

// Round 9
// 196.821 us; speedup vs baseline: 1.2045x; 1.2045x over previous
//
#include <hip/hip_runtime.h>

// ---------------------------------------------------------------------------
// LatentMixtureAllRNNAgent: per-agent fc1 -> GRU cell -> fc2 on MI355X.
// Round 9: round-8's wave-level zero-LDS gate kernel with a LOCALITY-FIXED
// mapping. R8 lesson: cs-outer/rt-inner block order re-streamed X/H 8x from
// HBM (FETCH 201MB) and scattered partial-line h writes (WRITE 260MB).
// Now: 2048 x 256-thread blocks, 4 waves = 4 col-slices of the SAME 32 rows
// (A reuse via L1, no barriers, no LDS); consecutive bids cover all 8 slices
// of a row-tile (write merge in L2); agent = bid&7 pins weights per XCD L2.
// Numerics identical to round 8 (absmax 1.0).
// ---------------------------------------------------------------------------

typedef __attribute__((ext_vector_type(4))) float f32x4;
typedef __attribute__((ext_vector_type(8))) short s8;     // 8 bf16 (4 VGPRs)
typedef __attribute__((ext_vector_type(4))) unsigned short us4;
typedef __attribute__((ext_vector_type(8))) unsigned short us8;

#define QSIZE   983040      /* 32768*30 */
#define W1H_OFF 0
#define W1L_OFF 524288
#define WIH_OFF 1048576
#define WHH_OFF 2621440
#define W2T_OFF 4194304
#define XB_OFF  4259840                 /* X bf16: 32768*256 */
#define HB_OFF  12648448                /* h_in bf16: 32768*256 */
#define WS_NEED_NEW 42074112ull        /* (HB_OFF + 8388608)*2 bytes */

static __device__ __forceinline__ unsigned short f2bf(float f) {
  union { float f; unsigned u; } v; v.f = f;
  unsigned r = v.u + 0x7FFFu + ((v.u >> 16) & 1u);   // RNE
  return (unsigned short)(r >> 16);
}
static __device__ __forceinline__ float bf2f(unsigned short u) {
  union { unsigned u; float f; } v; v.u = ((unsigned)u) << 16;
  return v.f;
}
static __device__ __forceinline__ float sigm(float x) {
  return 1.0f / (1.0f + __expf(-x));
}
static __device__ __forceinline__ float tanh_(float x) {
  return 1.0f - 2.0f / (__expf(2.0f * x) + 1.0f);
}

// ------------- prep: f32 [a][k][n] -> bf16 [a][n][k] planes in ws -----------
__global__ void prep_weights(const float* __restrict__ fc1w,
                             const float* __restrict__ rihw,
                             const float* __restrict__ rhhw,
                             const float* __restrict__ fc2w,
                             unsigned short* __restrict__ ws) {
  int q = blockIdx.x * 256 + threadIdx.x;
  if (q < 131072) {                         // fc1: hi + lo planes
    int a = q >> 14, rem = q & 16383, k4 = rem >> 8, n = rem & 255;
    const float* s = fc1w + a * 65536 + (k4 * 4) * 256 + n;
    float v0 = s[0], v1 = s[256], v2 = s[512], v3 = s[768];
    us4 hi = { f2bf(v0), f2bf(v1), f2bf(v2), f2bf(v3) };
    us4 lo = { f2bf(v0 - bf2f(hi[0])), f2bf(v1 - bf2f(hi[1])),
               f2bf(v2 - bf2f(hi[2])), f2bf(v3 - bf2f(hi[3])) };
    int o = ((a * 256 + n) << 8) + k4 * 4;
    *(us4*)(ws + W1H_OFF + o) = hi;
    *(us4*)(ws + W1L_OFF + o) = lo;
  } else if (q < 524288) {                  // rnn_ih, centered (w - 0.5)
    int t = q - 131072;
    int a = t / 49152, rem = t % 49152, k4 = rem / 768, n = rem % 768;
    const float* s = rihw + a * 196608 + (k4 * 4) * 768 + n;
    us4 v = { f2bf(s[0] - 0.5f), f2bf(s[768] - 0.5f),
              f2bf(s[1536] - 0.5f), f2bf(s[2304] - 0.5f) };
    *(us4*)(ws + WIH_OFF + ((a * 768 + n) << 8) + k4 * 4) = v;
  } else if (q < 917504) {                  // rnn_hh, centered
    int t = q - 524288;
    int a = t / 49152, rem = t % 49152, k4 = rem / 768, n = rem % 768;
    const float* s = rhhw + a * 196608 + (k4 * 4) * 768 + n;
    us4 v = { f2bf(s[0] - 0.5f), f2bf(s[768] - 0.5f),
              f2bf(s[1536] - 0.5f), f2bf(s[2304] - 0.5f) };
    *(us4*)(ws + WHH_OFF + ((a * 768 + n) << 8) + k4 * 4) = v;
  } else if (q < 933888) {                  // fc2: plain, pad 30->32
    int t = q - 917504;
    int a = t >> 11, rem = t & 2047, k4 = rem >> 5, n = rem & 31;
    us4 v = { 0, 0, 0, 0 };
    if (n < 30) {
      const float* s = fc2w + a * 7680 + (k4 * 4) * 30 + n;
      v = (us4){ f2bf(s[0]), f2bf(s[30]), f2bf(s[60]), f2bf(s[90]) };
    }
    *(us4*)(ws + W2T_OFF + ((a * 32 + n) << 8) + k4 * 4) = v;
  }
}

// ------- stage 32x256 f32 tile -> split bf16 (hi p0, lo p1), 256 thr --------
static __device__ __forceinline__ void stage_split(unsigned short* p0,
                                                   unsigned short* p1,
                                                   const float* __restrict__ src,
                                                   int rowbase, int a, int tid) {
#pragma unroll
  for (int k = 0; k < 8; ++k) {
    int j = tid + k * 256;
    int r = j >> 6;
    int c4 = (j & 63) << 2;
    const float* p = src + ((((rowbase + r) << 3) + a) << 8) + c4;
    float4 v = *(const float4*)p;
    us4 hi = { f2bf(v.x), f2bf(v.y), f2bf(v.z), f2bf(v.w) };
    us4 lo = { f2bf(v.x - bf2f(hi[0])), f2bf(v.y - bf2f(hi[1])),
               f2bf(v.z - bf2f(hi[2])), f2bf(v.w - bf2f(hi[3])) };
    int idx = ((r << 8) + c4) ^ ((r & 7) << 3);   // XOR swizzle (16B blocks)
    *(us4*)(p0 + idx) = hi;
    *(us4*)(p1 + idx) = lo;
  }
}

// ------------- stage 32x256 f32 tile -> single bf16 plane, 256 thr ----------
static __device__ __forceinline__ void stage_single(unsigned short* p,
                                                    const float* __restrict__ src,
                                                    int rowbase, int a, int tid) {
#pragma unroll
  for (int k = 0; k < 8; ++k) {
    int j = tid + k * 256;
    int r = j >> 6;
    int c4 = (j & 63) << 2;
    const float* sp = src + ((((rowbase + r) << 3) + a) << 8) + c4;
    float4 v = *(const float4*)sp;
    us4 hi = { f2bf(v.x), f2bf(v.y), f2bf(v.z), f2bf(v.w) };
    int idx = ((r << 8) + c4) ^ ((r & 7) << 3);
    *(us4*)(p + idx) = hi;
  }
}

// ---- 32x64 tile GEMM over K=256: acc[2][4] += A_lds @ Wt^T -----------------
static __device__ __forceinline__ void mma64(const unsigned short* lds,
                                             const unsigned short* __restrict__ wt,
                                             int n0, int l16, int l4,
                                             f32x4 (&acc)[2][4]) {
#pragma unroll
  for (int ks = 0; ks < 8; ++ks) {
    s8 af[2], bw[4];
#pragma unroll
    for (int mt = 0; mt < 2; ++mt) {
      int row = mt * 16 + l16;
      int idx = ((row << 8) + ks * 32 + 8 * l4) ^ ((row & 7) << 3);
      af[mt] = *(const s8*)(lds + idx);
    }
#pragma unroll
    for (int nt = 0; nt < 4; ++nt) {
      bw[nt] = *(const s8*)(wt + ((n0 + nt * 16 + l16) << 8) + ks * 32 + 8 * l4);
    }
#pragma unroll
    for (int mt = 0; mt < 2; ++mt)
#pragma unroll
      for (int nt = 0; nt < 4; ++nt)
        acc[mt][nt] = __builtin_amdgcn_mfma_f32_16x16x32_bf16(
            af[mt], bw[nt], acc[mt][nt], 0, 0, 0);
  }
}

// ========================== K1: fc1 -> X bf16 (ws) [+ h_in bf16] ===========
__global__ __launch_bounds__(256, 2) void k1_fc1(
    const float* __restrict__ inp, const float* __restrict__ hin,
    const float* __restrict__ b1, unsigned short* __restrict__ ws, int whb) {
  __shared__ __align__(16) unsigned short P0[32 * 256];
  __shared__ __align__(16) unsigned short P1[32 * 256];
  const int tid = threadIdx.x;
  const int a = blockIdx.x & 7;
  const int rowbase = (blockIdx.x >> 3) * 32;
  const int lane = tid & 63, w = tid >> 6;
  const int l16 = lane & 15, l4 = lane >> 4;
  const int n0 = w * 64;

  stage_split(P0, P1, inp, rowbase, a, tid);

  if (whb) {      // stage h_in -> bf16 in ws (straight copy, no LDS)
#pragma unroll
    for (int k = 0; k < 8; ++k) {
      int j = tid + k * 256;
      int r = j >> 6;
      int c4 = (j & 63) << 2;
      int flat = ((rowbase + r) << 3) + a;
      float4 v = *(const float4*)(hin + (flat << 8) + c4);
      us4 u = { f2bf(v.x), f2bf(v.y), f2bf(v.z), f2bf(v.w) };
      *(us4*)(ws + HB_OFF + (flat << 8) + c4) = u;
    }
  }
  __syncthreads();

  f32x4 XA[2][4];
#pragma unroll
  for (int mt = 0; mt < 2; ++mt)
#pragma unroll
    for (int nt = 0; nt < 4; ++nt) XA[mt][nt] = (f32x4){0.f, 0.f, 0.f, 0.f};
  mma64(P0, ws + W1H_OFF + a * 65536, n0, l16, l4, XA);
  mma64(P1, ws + W1H_OFF + a * 65536, n0, l16, l4, XA);
  mma64(P0, ws + W1L_OFF + a * 65536, n0, l16, l4, XA);

#pragma unroll
  for (int nt = 0; nt < 4; ++nt) {
    int col = n0 + nt * 16 + l16;
    float bb = b1[a * 256 + col];
#pragma unroll
    for (int mt = 0; mt < 2; ++mt)
#pragma unroll
      for (int r = 0; r < 4; ++r) {
        float v = fmaxf(XA[mt][nt][r] + bb, 0.f);
        int row = mt * 16 + l4 * 4 + r;
        int flat = ((rowbase + row) << 3) + a;
        ws[XB_OFF + (flat << 8) + col] = f2bf(v);
      }
  }
}

// ====== K2: 4-wave blocks, wave = one 32-col slice of shared 32 rows ========
__global__ __launch_bounds__(256, 2) void k2_gates_nw(
    const float* __restrict__ bih, const float* __restrict__ bhh,
    const unsigned short* __restrict__ ws, float* __restrict__ out) {
  const int tid = threadIdx.x & 63;      // lane
  const int w   = threadIdx.x >> 6;      // wave 0..3
  const int bid = blockIdx.x;
  const int a   = bid & 7;               // agent == XCD (weights L2-pinned)
  const int g   = bid >> 3;              // 0..255
  const int rt  = g >> 1;                // row-tile 0..127 (SLOW)
  const int csg = g & 1;                 // col-slice group (FAST)
  const int cs  = csg * 4 + w;           // wave's col-slice 0..7
  const int rowbase = rt * 32;
  const int n0  = cs * 32;
  const int l16 = tid & 15, l4 = tid >> 4;

  const unsigned short* WihA = ws + WIH_OFF + a * 196608;
  const unsigned short* WhhA = ws + WHH_OFF + a * 196608;

  // per-lane A-fragment bases: rows (rowbase + mt*16 + l16), k offset 8*l4
  const unsigned short* ax0 = ws + XB_OFF + ((((rowbase + l16)      << 3) + a) << 8) + 8 * l4;
  const unsigned short* ax1 = ws + XB_OFF + ((((rowbase + 16 + l16) << 3) + a) << 8) + 8 * l4;
  const unsigned short* ah0 = ws + HB_OFF + ((((rowbase + l16)      << 3) + a) << 8) + 8 * l4;
  const unsigned short* ah1 = ws + HB_OFF + ((((rowbase + 16 + l16) << 3) + a) << 8) + 8 * l4;

  s8 ones;
#pragma unroll
  for (int i = 0; i < 8; ++i) ones[i] = (short)0x3F80;   // bf16 1.0

  f32x4 R[2][2], T[2][2], SX[2], SH[2];
#pragma unroll
  for (int mt = 0; mt < 2; ++mt) {
    SX[mt] = (f32x4){0.f, 0.f, 0.f, 0.f};
    SH[mt] = (f32x4){0.f, 0.f, 0.f, 0.f};
#pragma unroll
    for (int nt = 0; nt < 2; ++nt) {
      R[mt][nt] = (f32x4){0.f, 0.f, 0.f, 0.f};
      T[mt][nt] = (f32x4){0.f, 0.f, 0.f, 0.f};
    }
  }

  // ---- phase 1: resetgate accs + exact rowsums (MFMA with ones-B) ----
#pragma unroll
  for (int ks = 0; ks < 8; ++ks) {
    s8 ax[2] = { *(const s8*)(ax0 + ks * 32), *(const s8*)(ax1 + ks * 32) };
    s8 ah[2] = { *(const s8*)(ah0 + ks * 32), *(const s8*)(ah1 + ks * 32) };
    s8 bx[2], bh[2];
#pragma unroll
    for (int nt = 0; nt < 2; ++nt) {
      int wrow = n0 + nt * 16 + l16;
      bx[nt] = *(const s8*)(WihA + (wrow << 8) + ks * 32 + 8 * l4);
      bh[nt] = *(const s8*)(WhhA + (wrow << 8) + ks * 32 + 8 * l4);
    }
#pragma unroll
    for (int mt = 0; mt < 2; ++mt) {
      SX[mt] = __builtin_amdgcn_mfma_f32_16x16x32_bf16(ax[mt], ones, SX[mt], 0, 0, 0);
      SH[mt] = __builtin_amdgcn_mfma_f32_16x16x32_bf16(ah[mt], ones, SH[mt], 0, 0, 0);
#pragma unroll
      for (int nt = 0; nt < 2; ++nt) {
        R[mt][nt] = __builtin_amdgcn_mfma_f32_16x16x32_bf16(ax[mt], bx[nt], R[mt][nt], 0, 0, 0);
        R[mt][nt] = __builtin_amdgcn_mfma_f32_16x16x32_bf16(ah[mt], bh[nt], R[mt][nt], 0, 0, 0);
      }
    }
  }
  // r = sigmoid(acc + 0.5*(rsx+rsh) + biases)
#pragma unroll
  for (int nt = 0; nt < 2; ++nt) {
    int col = n0 + nt * 16 + l16;
    float bb = bih[a * 768 + col] + bhh[a * 768 + col];
#pragma unroll
    for (int mt = 0; mt < 2; ++mt)
#pragma unroll
      for (int r = 0; r < 4; ++r)
        R[mt][nt][r] = sigm(R[mt][nt][r] + 0.5f * (SX[mt][r] + SH[mt][r]) + bb);
  }

  // ---- phase 2: T = h @ Whh_n ----
#pragma unroll
  for (int ks = 0; ks < 8; ++ks) {
    s8 ah[2] = { *(const s8*)(ah0 + ks * 32), *(const s8*)(ah1 + ks * 32) };
    s8 bn[2];
#pragma unroll
    for (int nt = 0; nt < 2; ++nt)
      bn[nt] = *(const s8*)(WhhA + ((512 + n0 + nt * 16 + l16) << 8) + ks * 32 + 8 * l4);
#pragma unroll
    for (int mt = 0; mt < 2; ++mt)
#pragma unroll
      for (int nt = 0; nt < 2; ++nt)
        T[mt][nt] = __builtin_amdgcn_mfma_f32_16x16x32_bf16(ah[mt], bn[nt], T[mt][nt], 0, 0, 0);
  }
  // T = r * (T + 0.5*rsh + bhh_n)
#pragma unroll
  for (int nt = 0; nt < 2; ++nt) {
    int col = n0 + nt * 16 + l16;
    float bb = bhh[a * 768 + 512 + col];
#pragma unroll
    for (int mt = 0; mt < 2; ++mt)
#pragma unroll
      for (int r = 0; r < 4; ++r)
        T[mt][nt][r] = R[mt][nt][r] * (T[mt][nt][r] + 0.5f * SH[mt][r] + bb);
  }

  // ---- phase 3: newgate — accumulate x @ Wih_n INTO T via MFMA C-in ----
#pragma unroll
  for (int ks = 0; ks < 8; ++ks) {
    s8 ax[2] = { *(const s8*)(ax0 + ks * 32), *(const s8*)(ax1 + ks * 32) };
    s8 bn[2];
#pragma unroll
    for (int nt = 0; nt < 2; ++nt)
      bn[nt] = *(const s8*)(WihA + ((512 + n0 + nt * 16 + l16) << 8) + ks * 32 + 8 * l4);
#pragma unroll
    for (int mt = 0; mt < 2; ++mt)
#pragma unroll
      for (int nt = 0; nt < 2; ++nt)
        T[mt][nt] = __builtin_amdgcn_mfma_f32_16x16x32_bf16(ax[mt], bn[nt], T[mt][nt], 0, 0, 0);
  }
  // T = tanh(T + 0.5*rsx + bih_n)
#pragma unroll
  for (int nt = 0; nt < 2; ++nt) {
    int col = n0 + nt * 16 + l16;
    float bb = bih[a * 768 + 512 + col];
#pragma unroll
    for (int mt = 0; mt < 2; ++mt)
#pragma unroll
      for (int r = 0; r < 4; ++r)
        T[mt][nt][r] = tanh_(T[mt][nt][r] + 0.5f * SX[mt][r] + bb);
  }

  // ---- phase 4: inputgate (reuse R), combine, store h ----
#pragma unroll
  for (int mt = 0; mt < 2; ++mt)
#pragma unroll
    for (int nt = 0; nt < 2; ++nt) R[mt][nt] = (f32x4){0.f, 0.f, 0.f, 0.f};
#pragma unroll
  for (int ks = 0; ks < 8; ++ks) {
    s8 ax[2] = { *(const s8*)(ax0 + ks * 32), *(const s8*)(ax1 + ks * 32) };
    s8 ah[2] = { *(const s8*)(ah0 + ks * 32), *(const s8*)(ah1 + ks * 32) };
    s8 bx[2], bh[2];
#pragma unroll
    for (int nt = 0; nt < 2; ++nt) {
      int wrow = 256 + n0 + nt * 16 + l16;
      bx[nt] = *(const s8*)(WihA + (wrow << 8) + ks * 32 + 8 * l4);
      bh[nt] = *(const s8*)(WhhA + (wrow << 8) + ks * 32 + 8 * l4);
    }
#pragma unroll
    for (int mt = 0; mt < 2; ++mt)
#pragma unroll
      for (int nt = 0; nt < 2; ++nt) {
        R[mt][nt] = __builtin_amdgcn_mfma_f32_16x16x32_bf16(ax[mt], bx[nt], R[mt][nt], 0, 0, 0);
        R[mt][nt] = __builtin_amdgcn_mfma_f32_16x16x32_bf16(ah[mt], bh[nt], R[mt][nt], 0, 0, 0);
      }
  }
#pragma unroll
  for (int nt = 0; nt < 2; ++nt) {
    int col = n0 + nt * 16 + l16;
    float bb = bih[a * 768 + 256 + col] + bhh[a * 768 + 256 + col];
#pragma unroll
    for (int mt = 0; mt < 2; ++mt)
#pragma unroll
      for (int r = 0; r < 4; ++r) {
        int row = mt * 16 + l4 * 4 + r;
        int flat = ((rowbase + row) << 3) + a;
        float ig = sigm(R[mt][nt][r] + 0.5f * (SX[mt][r] + SH[mt][r]) + bb);
        float hv = bf2f(ws[HB_OFF + (flat << 8) + col]);
        float ng = T[mt][nt][r];
        out[QSIZE + (flat << 8) + col] = ng + ig * (hv - ng);
      }
  }
}

// ========================== K3: fc2 -> q (out) ==============================
__global__ __launch_bounds__(128) void k3_fc2(
    const float* __restrict__ b2, const unsigned short* __restrict__ ws,
    float* __restrict__ out) {
  __shared__ __align__(16) unsigned short HB[32 * 256];
  const int tid = threadIdx.x;
  const int a = blockIdx.x & 7;
  const int rowbase = (blockIdx.x >> 3) * 32;
  const int lane = tid & 63, w = tid >> 6;
  const int l16 = lane & 15, l4 = lane >> 4;

#pragma unroll
  for (int k = 0; k < 16; ++k) {
    int j = tid + k * 128;
    int r = j >> 6;
    int c4 = (j & 63) << 2;
    const float* sp = out + QSIZE + ((((rowbase + r) << 3) + a) << 8) + c4;
    float4 v = *(const float4*)sp;
    us4 hi = { f2bf(v.x), f2bf(v.y), f2bf(v.z), f2bf(v.w) };
    int idx = ((r << 8) + c4) ^ ((r & 7) << 3);
    *(us4*)(HB + idx) = hi;
  }
  __syncthreads();

  f32x4 qa[2];
  qa[0] = (f32x4){0.f, 0.f, 0.f, 0.f};
  qa[1] = (f32x4){0.f, 0.f, 0.f, 0.f};
#pragma unroll
  for (int ks = 0; ks < 8; ++ks) {
    int row = w * 16 + l16;
    int idx = ((row << 8) + ks * 32 + 8 * l4) ^ ((row & 7) << 3);
    s8 af = *(const s8*)(HB + idx);
#pragma unroll
    for (int nt = 0; nt < 2; ++nt) {
      s8 bw = *(const s8*)(ws + W2T_OFF + ((a * 32 + nt * 16 + l16) << 8) + ks * 32 + 8 * l4);
      qa[nt] = __builtin_amdgcn_mfma_f32_16x16x32_bf16(af, bw, qa[nt], 0, 0, 0);
    }
  }
#pragma unroll
  for (int nt = 0; nt < 2; ++nt) {
    int col = nt * 16 + l16;
    if (col < 30) {
      float bb = b2[a * 30 + col];
#pragma unroll
      for (int r = 0; r < 4; ++r) {
        int row = w * 16 + l4 * 4 + r;
        out[(((rowbase + row) << 3) + a) * 30 + col] = fmaxf(qa[nt][r] + bb, 0.f);
      }
    }
  }
}

// ============ K2 (old, round-7 wide): fallback when ws < 42 MB ==============
__global__ __launch_bounds__(256, 1) void k2_gates(
    const float* __restrict__ hin, const float* __restrict__ bih,
    const float* __restrict__ bhh, const unsigned short* __restrict__ ws,
    float* __restrict__ out) {
  __shared__ __align__(16) unsigned short P0[32 * 256];
  __shared__ __align__(16) unsigned short P1[32 * 256];
  __shared__ float RSXP[8][32], RSHP[8][32];
  __shared__ float RSX[32], RSH[32];

  const int tid = threadIdx.x;
  const int a = blockIdx.x & 7;
  const int rowbase = (blockIdx.x >> 3) * 32;
  const int lane = tid & 63, w = tid >> 6;
  const int l16 = lane & 15, l4 = lane >> 4;
  const int n0 = w * 64;

#pragma unroll
  for (int k = 0; k < 4; ++k) {
    int j = tid + k * 256;
    int r = j >> 5;
    int c = (j & 31) << 3;
    us8 v = *(const us8*)(ws + XB_OFF + ((((rowbase + r) << 3) + a) << 8) + c);
    int idx = ((r << 8) + c) ^ ((r & 7) << 3);
    *(us8*)(P0 + idx) = v;
  }
  stage_single(P1, hin, rowbase, a, tid);
  __syncthreads();

  {
    int row = tid >> 3, qd = tid & 7;
    float sx = 0.f, sh = 0.f;
#pragma unroll
    for (int i = 0; i < 8; ++i) {
      int c = qd * 32 + i * 4;
      int idx = ((row << 8) + c) ^ ((row & 7) << 3);
      us4 vx = *(const us4*)(P0 + idx);
      us4 vh = *(const us4*)(P1 + idx);
      sx += bf2f(vx[0]) + bf2f(vx[1]) + bf2f(vx[2]) + bf2f(vx[3]);
      sh += bf2f(vh[0]) + bf2f(vh[1]) + bf2f(vh[2]) + bf2f(vh[3]);
    }
    RSXP[qd][row] = sx; RSHP[qd][row] = sh;
  }
  __syncthreads();
  if (tid < 32) {
    float sx = 0.f, sh = 0.f;
#pragma unroll
    for (int qd = 0; qd < 8; ++qd) { sx += RSXP[qd][tid]; sh += RSHP[qd][tid]; }
    RSX[tid] = sx; RSH[tid] = sh;
  }
  __syncthreads();

  const unsigned short* WihA = ws + WIH_OFF + a * 768 * 256;
  const unsigned short* WhhA = ws + WHH_OFF + a * 768 * 256;

  f32x4 R[2][4], T[2][4];
#pragma unroll
  for (int mt = 0; mt < 2; ++mt)
#pragma unroll
    for (int nt = 0; nt < 4; ++nt) R[mt][nt] = (f32x4){0.f, 0.f, 0.f, 0.f};
  mma64(P0, WihA, n0, l16, l4, R);
  mma64(P1, WhhA, n0, l16, l4, R);
#pragma unroll
  for (int nt = 0; nt < 4; ++nt) {
    int col = n0 + nt * 16 + l16;
    float bb = bih[a * 768 + col] + bhh[a * 768 + col];
#pragma unroll
    for (int mt = 0; mt < 2; ++mt)
#pragma unroll
      for (int r = 0; r < 4; ++r) {
        int row = mt * 16 + l4 * 4 + r;
        R[mt][nt][r] = sigm(R[mt][nt][r] + 0.5f * (RSX[row] + RSH[row]) + bb);
      }
  }
#pragma unroll
  for (int mt = 0; mt < 2; ++mt)
#pragma unroll
    for (int nt = 0; nt < 4; ++nt) T[mt][nt] = (f32x4){0.f, 0.f, 0.f, 0.f};
  mma64(P1, WhhA + 512 * 256, n0, l16, l4, T);
#pragma unroll
  for (int nt = 0; nt < 4; ++nt) {
    int col = n0 + nt * 16 + l16;
    float bb = bhh[a * 768 + 512 + col];
#pragma unroll
    for (int mt = 0; mt < 2; ++mt)
#pragma unroll
      for (int r = 0; r < 4; ++r) {
        int row = mt * 16 + l4 * 4 + r;
        T[mt][nt][r] = R[mt][nt][r] * (T[mt][nt][r] + 0.5f * RSH[row] + bb);
      }
  }
  mma64(P0, WihA + 512 * 256, n0, l16, l4, T);
#pragma unroll
  for (int nt = 0; nt < 4; ++nt) {
    int col = n0 + nt * 16 + l16;
    float bb = bih[a * 768 + 512 + col];
#pragma unroll
    for (int mt = 0; mt < 2; ++mt)
#pragma unroll
      for (int r = 0; r < 4; ++r) {
        int row = mt * 16 + l4 * 4 + r;
        T[mt][nt][r] = tanh_(T[mt][nt][r] + 0.5f * RSX[row] + bb);
      }
  }
#pragma unroll
  for (int mt = 0; mt < 2; ++mt)
#pragma unroll
    for (int nt = 0; nt < 4; ++nt) R[mt][nt] = (f32x4){0.f, 0.f, 0.f, 0.f};
  mma64(P0, WihA + 256 * 256, n0, l16, l4, R);
  mma64(P1, WhhA + 256 * 256, n0, l16, l4, R);
#pragma unroll
  for (int nt = 0; nt < 4; ++nt) {
    int col = n0 + nt * 16 + l16;
    float bb = bih[a * 768 + 256 + col] + bhh[a * 768 + 256 + col];
#pragma unroll
    for (int mt = 0; mt < 2; ++mt)
#pragma unroll
      for (int r = 0; r < 4; ++r) {
        int row = mt * 16 + l4 * 4 + r;
        float ig = sigm(R[mt][nt][r] + 0.5f * (RSX[row] + RSH[row]) + bb);
        float hv = bf2f(P1[((row << 8) + col) ^ ((row & 7) << 3)]);
        float ng = T[mt][nt][r];
        out[QSIZE + ((((rowbase + row) << 3) + a) << 8) + col]
            = ng + ig * (hv - ng);
      }
  }
}

extern "C" void kernel_launch(void* const* d_in, const int* in_sizes, int n_in,
                              void* d_out, int out_size, void* d_ws, size_t ws_size,
                              hipStream_t stream) {
  const float* inputs = (const float*)d_in[0];
  const float* hidden = (const float*)d_in[1];
  const float* fc1w   = (const float*)d_in[2];
  const float* fc1b   = (const float*)d_in[3];
  const float* rihw   = (const float*)d_in[4];
  const float* rihb   = (const float*)d_in[5];
  const float* rhhw   = (const float*)d_in[6];
  const float* rhhb   = (const float*)d_in[7];
  const float* fc2w   = (const float*)d_in[8];
  const float* fc2b   = (const float*)d_in[9];
  unsigned short* ws  = (unsigned short*)d_ws;
  float* out          = (float*)d_out;

  hipLaunchKernelGGL(prep_weights, dim3(3648), dim3(256), 0, stream,
                     fc1w, rihw, rhhw, fc2w, ws);

  if (ws_size >= WS_NEED_NEW) {
    hipLaunchKernelGGL(k1_fc1, dim3(1024), dim3(256), 0, stream,
                       inputs, hidden, fc1b, ws, 1);
    hipLaunchKernelGGL(k2_gates_nw, dim3(2048), dim3(256), 0, stream,
                       rihb, rhhb, ws, out);
    hipLaunchKernelGGL(k3_fc2, dim3(1024), dim3(128), 0, stream, fc2b, ws, out);
  } else {
    hipLaunchKernelGGL(k1_fc1, dim3(1024), dim3(256), 0, stream,
                       inputs, hidden, fc1b, ws, 0);
    hipLaunchKernelGGL(k2_gates, dim3(1024), dim3(256), 0, stream,
                       hidden, rihb, rhhb, ws, out);
    hipLaunchKernelGGL(k3_fc2, dim3(1024), dim3(128), 0, stream, fc2b, ws, out);
  }
}

// Round 10
// 129.466 us; speedup vs baseline: 1.8311x; 1.5203x over previous
//
#include <hip/hip_runtime.h>

// ---------------------------------------------------------------------------
// LatentMixtureAllRNNAgent: per-agent fc1 -> GRU cell -> fc2 on MI355X.
// Round 10: FRAGMENT-MAJOR layouts. Round-9 k2 was transaction-bound: every
// s8 operand load gathered 16 cache lines (A rows 4KB apart, W rows 512B
// apart) -> ~128 L1 transactions per ks-iter. Now X, h_in and ALL weights are
// stored in MFMA fragment order [blk16][ks][l4][l16][8], so every operand
// load is ONE contiguous 1KB wave-load. k1 bounces X/h_in through LDS to
// write fragments coalesced. k2 merges the Whh_n/Wih_n passes (independent
// accs, 2x ILP) and reads h_in for the combine from f32 hin (coalesced).
// Numerics: same as rounds 2-9 (absmax 1.0); combine hv now f32 (better).
// ---------------------------------------------------------------------------

typedef __attribute__((ext_vector_type(4))) float f32x4;
typedef __attribute__((ext_vector_type(8))) short s8;     // 8 bf16 (4 VGPRs)
typedef __attribute__((ext_vector_type(4))) unsigned short us4;
typedef __attribute__((ext_vector_type(8))) unsigned short us8;

#define QSIZE   983040      /* 32768*30 */
#define W1H_OFF 0
#define W1L_OFF 524288
#define WIH_OFF 1048576
#define WHH_OFF 2621440
#define W2T_OFF 4194304
#define XB_OFF  4259840                 /* X fragments:   8a x 256rb x 4096 */
#define HB_OFF  12648448                /* h_in fragments: same */
#define WS_NEED_NEW 42074112ull

static __device__ __forceinline__ unsigned short f2bf(float f) {
  union { float f; unsigned u; } v; v.f = f;
  unsigned r = v.u + 0x7FFFu + ((v.u >> 16) & 1u);   // RNE
  return (unsigned short)(r >> 16);
}
static __device__ __forceinline__ float bf2f(unsigned short u) {
  union { unsigned u; float f; } v; v.u = ((unsigned)u) << 16;
  return v.f;
}
static __device__ __forceinline__ float sigm(float x) {
  return 1.0f / (1.0f + __expf(-x));
}
static __device__ __forceinline__ float tanh_(float x) {
  return 1.0f - 2.0f / (__expf(2.0f * x) + 1.0f);
}

// ---- prep: f32 [a][k][n] -> bf16 fragment layout [a][cb][ks][l4][l16][8] ---
__global__ void prep_weights(const float* __restrict__ fc1w,
                             const float* __restrict__ rihw,
                             const float* __restrict__ rhhw,
                             const float* __restrict__ fc2w,
                             unsigned short* __restrict__ ws) {
  int q = blockIdx.x * 256 + threadIdx.x;   // one us4 (4 k-values) per thread
  if (q < 131072) {                         // fc1: hi + lo, 8a x 16cb x 1024
    int a = q >> 14, rem = q & 16383;
    int cb = rem >> 10, s = rem & 1023;
    int ks = s >> 7, l4 = (s >> 5) & 3, l16 = (s >> 1) & 15, hf = s & 1;
    int n = cb * 16 + l16, k0 = ks * 32 + l4 * 8 + hf * 4;
    const float* sp = fc1w + a * 65536 + k0 * 256 + n;
    float v0 = sp[0], v1 = sp[256], v2 = sp[512], v3 = sp[768];
    us4 hi = { f2bf(v0), f2bf(v1), f2bf(v2), f2bf(v3) };
    us4 lo = { f2bf(v0 - bf2f(hi[0])), f2bf(v1 - bf2f(hi[1])),
               f2bf(v2 - bf2f(hi[2])), f2bf(v3 - bf2f(hi[3])) };
    int o = a * 65536 + cb * 4096 + ks * 512 + l4 * 128 + l16 * 8 + hf * 4;
    *(us4*)(ws + W1H_OFF + o) = hi;
    *(us4*)(ws + W1L_OFF + o) = lo;
  } else if (q < 524288) {                  // rnn_ih centered: 8a x 48cb
    int t = q - 131072;
    int a = t / 49152, rem = t % 49152;
    int cb = rem >> 10, s = rem & 1023;
    int ks = s >> 7, l4 = (s >> 5) & 3, l16 = (s >> 1) & 15, hf = s & 1;
    int n = cb * 16 + l16, k0 = ks * 32 + l4 * 8 + hf * 4;
    const float* sp = rihw + a * 196608 + k0 * 768 + n;
    us4 v = { f2bf(sp[0] - 0.5f), f2bf(sp[768] - 0.5f),
              f2bf(sp[1536] - 0.5f), f2bf(sp[2304] - 0.5f) };
    *(us4*)(ws + WIH_OFF + a * 196608 + cb * 4096 + ks * 512 + l4 * 128
            + l16 * 8 + hf * 4) = v;
  } else if (q < 917504) {                  // rnn_hh centered
    int t = q - 524288;
    int a = t / 49152, rem = t % 49152;
    int cb = rem >> 10, s = rem & 1023;
    int ks = s >> 7, l4 = (s >> 5) & 3, l16 = (s >> 1) & 15, hf = s & 1;
    int n = cb * 16 + l16, k0 = ks * 32 + l4 * 8 + hf * 4;
    const float* sp = rhhw + a * 196608 + k0 * 768 + n;
    us4 v = { f2bf(sp[0] - 0.5f), f2bf(sp[768] - 0.5f),
              f2bf(sp[1536] - 0.5f), f2bf(sp[2304] - 0.5f) };
    *(us4*)(ws + WHH_OFF + a * 196608 + cb * 4096 + ks * 512 + l4 * 128
            + l16 * 8 + hf * 4) = v;
  } else if (q < 933888) {                  // fc2: 8a x 2cb, pad n>=30 -> 0
    int t = q - 917504;
    int a = t >> 11, rem = t & 2047;
    int cb = rem >> 10, s = rem & 1023;
    int ks = s >> 7, l4 = (s >> 5) & 3, l16 = (s >> 1) & 15, hf = s & 1;
    int n = cb * 16 + l16, k0 = ks * 32 + l4 * 8 + hf * 4;
    us4 v = { 0, 0, 0, 0 };
    if (n < 30) {
      const float* sp = fc2w + a * 7680 + k0 * 30 + n;
      v = (us4){ f2bf(sp[0]), f2bf(sp[30]), f2bf(sp[60]), f2bf(sp[90]) };
    }
    *(us4*)(ws + W2T_OFF + a * 8192 + cb * 4096 + ks * 512 + l4 * 128
            + l16 * 8 + hf * 4) = v;
  }
}

// ------- stage 32x256 f32 tile -> split bf16 (hi p0, lo p1), 256 thr --------
static __device__ __forceinline__ void stage_split(unsigned short* p0,
                                                   unsigned short* p1,
                                                   const float* __restrict__ src,
                                                   int rowbase, int a, int tid) {
#pragma unroll
  for (int k = 0; k < 8; ++k) {
    int j = tid + k * 256;
    int r = j >> 6;
    int c4 = (j & 63) << 2;
    const float* p = src + ((((rowbase + r) << 3) + a) << 8) + c4;
    float4 v = *(const float4*)p;
    us4 hi = { f2bf(v.x), f2bf(v.y), f2bf(v.z), f2bf(v.w) };
    us4 lo = { f2bf(v.x - bf2f(hi[0])), f2bf(v.y - bf2f(hi[1])),
               f2bf(v.z - bf2f(hi[2])), f2bf(v.w - bf2f(hi[3])) };
    int idx = ((r << 8) + c4) ^ ((r & 7) << 3);   // XOR swizzle (16B blocks)
    *(us4*)(p0 + idx) = hi;
    *(us4*)(p1 + idx) = lo;
  }
}

// ------------- stage 32x256 f32 tile -> single bf16 plane, 256 thr ----------
static __device__ __forceinline__ void stage_single(unsigned short* p,
                                                    const float* __restrict__ src,
                                                    int rowbase, int a, int tid) {
#pragma unroll
  for (int k = 0; k < 8; ++k) {
    int j = tid + k * 256;
    int r = j >> 6;
    int c4 = (j & 63) << 2;
    const float* sp = src + ((((rowbase + r) << 3) + a) << 8) + c4;
    float4 v = *(const float4*)sp;
    us4 hi = { f2bf(v.x), f2bf(v.y), f2bf(v.z), f2bf(v.w) };
    int idx = ((r << 8) + c4) ^ ((r & 7) << 3);
    *(us4*)(p + idx) = hi;
  }
}

// ---- 32x64 GEMM over K=256, B from fragment layout (contiguous loads) ------
static __device__ __forceinline__ void mma64f(const unsigned short* lds,
                                              const unsigned short* __restrict__ wf,
                                              int cb0, int lane, int l16, int l4,
                                              f32x4 (&acc)[2][4]) {
#pragma unroll
  for (int ks = 0; ks < 8; ++ks) {
    s8 af[2], bw[4];
#pragma unroll
    for (int mt = 0; mt < 2; ++mt) {
      int row = mt * 16 + l16;
      int idx = ((row << 8) + ks * 32 + 8 * l4) ^ ((row & 7) << 3);
      af[mt] = *(const s8*)(lds + idx);
    }
#pragma unroll
    for (int nt = 0; nt < 4; ++nt)
      bw[nt] = *(const s8*)(wf + (cb0 + nt) * 4096 + ks * 512 + lane * 8);
#pragma unroll
    for (int mt = 0; mt < 2; ++mt)
#pragma unroll
      for (int nt = 0; nt < 4; ++nt)
        acc[mt][nt] = __builtin_amdgcn_mfma_f32_16x16x32_bf16(
            af[mt], bw[nt], acc[mt][nt], 0, 0, 0);
  }
}

// ---- 32x16 GEMM over K=256, fragment B (fallback kernel) -------------------
static __device__ __forceinline__ void mma16f(const unsigned short* lds,
                                              const unsigned short* __restrict__ wf,
                                              int cb, int lane, int l16, int l4,
                                              f32x4 (&acc)[2]) {
#pragma unroll
  for (int ks = 0; ks < 8; ++ks) {
    s8 bw = *(const s8*)(wf + cb * 4096 + ks * 512 + lane * 8);
#pragma unroll
    for (int mt = 0; mt < 2; ++mt) {
      int row = mt * 16 + l16;
      int idx = ((row << 8) + ks * 32 + 8 * l4) ^ ((row & 7) << 3);
      s8 af = *(const s8*)(lds + idx);
      acc[mt] = __builtin_amdgcn_mfma_f32_16x16x32_bf16(af, bw, acc[mt], 0, 0, 0);
    }
  }
}

// ====== K1: fc1 -> X fragments; h_in -> bf16 fragments (LDS bounce) =========
__global__ __launch_bounds__(256, 2) void k1_fc1(
    const float* __restrict__ inp, const float* __restrict__ hin,
    const float* __restrict__ b1, unsigned short* __restrict__ ws) {
  __shared__ __align__(16) unsigned short P0[32 * 256];
  __shared__ __align__(16) unsigned short P1[32 * 256];
  const int tid = threadIdx.x;
  const int a = blockIdx.x & 7;
  const int rt = blockIdx.x >> 3;
  const int rowbase = rt * 32;
  const int lane = tid & 63, w = tid >> 6;
  const int l16 = lane & 15, l4 = lane >> 4;
  const int n0 = w * 64;

  stage_split(P0, P1, inp, rowbase, a, tid);
  __syncthreads();

  f32x4 XA[2][4];
#pragma unroll
  for (int mt = 0; mt < 2; ++mt)
#pragma unroll
    for (int nt = 0; nt < 4; ++nt) XA[mt][nt] = (f32x4){0.f, 0.f, 0.f, 0.f};
  mma64f(P0, ws + W1H_OFF + a * 65536, w * 4, lane, l16, l4, XA);
  mma64f(P1, ws + W1H_OFF + a * 65536, w * 4, lane, l16, l4, XA);
  mma64f(P0, ws + W1L_OFF + a * 65536, w * 4, lane, l16, l4, XA);
  __syncthreads();                           // all LDS reads done

  // write x bf16 -> P0 (swizzled); stage h_in bf16 -> P1 (swizzled)
#pragma unroll
  for (int nt = 0; nt < 4; ++nt) {
    int col = n0 + nt * 16 + l16;
    float bb = b1[a * 256 + col];
#pragma unroll
    for (int mt = 0; mt < 2; ++mt)
#pragma unroll
      for (int r = 0; r < 4; ++r) {
        float v = fmaxf(XA[mt][nt][r] + bb, 0.f);
        int row = mt * 16 + l4 * 4 + r;
        P0[((row << 8) + col) ^ ((row & 7) << 3)] = f2bf(v);
      }
  }
  stage_single(P1, hin, rowbase, a, tid);
  __syncthreads();

  // fragment-dump: P0 -> XF, P1 -> HF (contiguous us8 wave stores)
  const int rbg = (a << 8) + rt * 2;
#pragma unroll
  for (int i = 0; i < 4; ++i) {
    int c = tid + i * 256;                   // 0..1023 us8 chunks
    int rb = c >> 9, s = c & 511;            // s = ks*64 + l4*16 + l16
    int row = rb * 16 + (s & 15);
    int col = ((s >> 6) << 5) + (((s >> 4) & 3) << 3);
    int idx = ((row << 8) + col) ^ ((row & 7) << 3);
    *(us8*)(ws + XB_OFF + (rbg + rb) * 4096 + s * 8) = *(const us8*)(P0 + idx);
    *(us8*)(ws + HB_OFF + (rbg + rb) * 4096 + s * 8) = *(const us8*)(P1 + idx);
  }
}

// ====== K2: 4-wave blocks, all operand loads = contiguous 1KB ===============
__global__ __launch_bounds__(256, 2) void k2_gates_nw(
    const float* __restrict__ hin, const float* __restrict__ bih,
    const float* __restrict__ bhh, const unsigned short* __restrict__ ws,
    float* __restrict__ out) {
  const int lane = threadIdx.x & 63;
  const int w    = threadIdx.x >> 6;
  const int bid  = blockIdx.x;
  const int a    = bid & 7;                 // agent == XCD
  const int g    = bid >> 3;
  const int rt   = g >> 1;                  // row-tile (slow)
  const int cs   = (g & 1) * 4 + w;         // col-slice 0..7
  const int rowbase = rt * 32;
  const int n0   = cs * 32;
  const int l16  = lane & 15, l4 = lane >> 4;

  const unsigned short* XF = ws + XB_OFF + ((a << 8) + rt * 2) * 4096;
  const unsigned short* HF = ws + HB_OFF + ((a << 8) + rt * 2) * 4096;
  const unsigned short* WihF = ws + WIH_OFF + a * 196608;
  const unsigned short* WhhF = ws + WHH_OFF + a * 196608;
  const int cbr = cs * 2;                   // reset cb; input +16; new +32

  s8 ones;
#pragma unroll
  for (int i = 0; i < 8; ++i) ones[i] = (short)0x3F80;

  f32x4 R[2][2], T[2][2], G[2][2], SX[2], SH[2];
#pragma unroll
  for (int mt = 0; mt < 2; ++mt) {
    SX[mt] = (f32x4){0.f, 0.f, 0.f, 0.f};
    SH[mt] = (f32x4){0.f, 0.f, 0.f, 0.f};
#pragma unroll
    for (int nt = 0; nt < 2; ++nt) {
      R[mt][nt] = (f32x4){0.f, 0.f, 0.f, 0.f};
      T[mt][nt] = (f32x4){0.f, 0.f, 0.f, 0.f};
      G[mt][nt] = (f32x4){0.f, 0.f, 0.f, 0.f};
    }
  }

  // ---- phase 1: resetgate accs + exact rowsums (MFMA with ones-B) ----
#pragma unroll
  for (int ks = 0; ks < 8; ++ks) {
    s8 ax[2], ah[2], bx[2], bh[2];
#pragma unroll
    for (int mt = 0; mt < 2; ++mt) {
      ax[mt] = *(const s8*)(XF + mt * 4096 + ks * 512 + lane * 8);
      ah[mt] = *(const s8*)(HF + mt * 4096 + ks * 512 + lane * 8);
    }
#pragma unroll
    for (int nt = 0; nt < 2; ++nt) {
      bx[nt] = *(const s8*)(WihF + (cbr + nt) * 4096 + ks * 512 + lane * 8);
      bh[nt] = *(const s8*)(WhhF + (cbr + nt) * 4096 + ks * 512 + lane * 8);
    }
#pragma unroll
    for (int mt = 0; mt < 2; ++mt) {
      SX[mt] = __builtin_amdgcn_mfma_f32_16x16x32_bf16(ax[mt], ones, SX[mt], 0, 0, 0);
      SH[mt] = __builtin_amdgcn_mfma_f32_16x16x32_bf16(ah[mt], ones, SH[mt], 0, 0, 0);
#pragma unroll
      for (int nt = 0; nt < 2; ++nt) {
        R[mt][nt] = __builtin_amdgcn_mfma_f32_16x16x32_bf16(ax[mt], bx[nt], R[mt][nt], 0, 0, 0);
        R[mt][nt] = __builtin_amdgcn_mfma_f32_16x16x32_bf16(ah[mt], bh[nt], R[mt][nt], 0, 0, 0);
      }
    }
  }
#pragma unroll
  for (int nt = 0; nt < 2; ++nt) {
    int col = n0 + nt * 16 + l16;
    float bb = bih[a * 768 + col] + bhh[a * 768 + col];
#pragma unroll
    for (int mt = 0; mt < 2; ++mt)
#pragma unroll
      for (int r = 0; r < 4; ++r)
        R[mt][nt][r] = sigm(R[mt][nt][r] + 0.5f * (SX[mt][r] + SH[mt][r]) + bb);
  }

  // ---- phase 2+3 merged: T = h@Whh_n ; G = x@Wih_n (independent, 2x ILP) --
#pragma unroll
  for (int ks = 0; ks < 8; ++ks) {
    s8 ax[2], ah[2], bnh[2], bnx[2];
#pragma unroll
    for (int mt = 0; mt < 2; ++mt) {
      ax[mt] = *(const s8*)(XF + mt * 4096 + ks * 512 + lane * 8);
      ah[mt] = *(const s8*)(HF + mt * 4096 + ks * 512 + lane * 8);
    }
#pragma unroll
    for (int nt = 0; nt < 2; ++nt) {
      bnh[nt] = *(const s8*)(WhhF + (32 + cbr + nt) * 4096 + ks * 512 + lane * 8);
      bnx[nt] = *(const s8*)(WihF + (32 + cbr + nt) * 4096 + ks * 512 + lane * 8);
    }
#pragma unroll
    for (int mt = 0; mt < 2; ++mt)
#pragma unroll
      for (int nt = 0; nt < 2; ++nt) {
        T[mt][nt] = __builtin_amdgcn_mfma_f32_16x16x32_bf16(ah[mt], bnh[nt], T[mt][nt], 0, 0, 0);
        G[mt][nt] = __builtin_amdgcn_mfma_f32_16x16x32_bf16(ax[mt], bnx[nt], G[mt][nt], 0, 0, 0);
      }
  }
  // T = tanh(G + 0.5*rsx + bih_n + r*(T + 0.5*rsh + bhh_n))
#pragma unroll
  for (int nt = 0; nt < 2; ++nt) {
    int col = n0 + nt * 16 + l16;
    float bbh = bhh[a * 768 + 512 + col];
    float bbi = bih[a * 768 + 512 + col];
#pragma unroll
    for (int mt = 0; mt < 2; ++mt)
#pragma unroll
      for (int r = 0; r < 4; ++r) {
        float t = R[mt][nt][r] * (T[mt][nt][r] + 0.5f * SH[mt][r] + bbh);
        T[mt][nt][r] = tanh_(G[mt][nt][r] + 0.5f * SX[mt][r] + bbi + t);
      }
  }

  // ---- phase 4: inputgate (reuse G), combine with f32 h_in, store h ----
#pragma unroll
  for (int mt = 0; mt < 2; ++mt)
#pragma unroll
    for (int nt = 0; nt < 2; ++nt) G[mt][nt] = (f32x4){0.f, 0.f, 0.f, 0.f};
#pragma unroll
  for (int ks = 0; ks < 8; ++ks) {
    s8 ax[2], ah[2], bx[2], bh[2];
#pragma unroll
    for (int mt = 0; mt < 2; ++mt) {
      ax[mt] = *(const s8*)(XF + mt * 4096 + ks * 512 + lane * 8);
      ah[mt] = *(const s8*)(HF + mt * 4096 + ks * 512 + lane * 8);
    }
#pragma unroll
    for (int nt = 0; nt < 2; ++nt) {
      bx[nt] = *(const s8*)(WihF + (16 + cbr + nt) * 4096 + ks * 512 + lane * 8);
      bh[nt] = *(const s8*)(WhhF + (16 + cbr + nt) * 4096 + ks * 512 + lane * 8);
    }
#pragma unroll
    for (int mt = 0; mt < 2; ++mt)
#pragma unroll
      for (int nt = 0; nt < 2; ++nt) {
        G[mt][nt] = __builtin_amdgcn_mfma_f32_16x16x32_bf16(ax[mt], bx[nt], G[mt][nt], 0, 0, 0);
        G[mt][nt] = __builtin_amdgcn_mfma_f32_16x16x32_bf16(ah[mt], bh[nt], G[mt][nt], 0, 0, 0);
      }
  }
#pragma unroll
  for (int nt = 0; nt < 2; ++nt) {
    int col = n0 + nt * 16 + l16;
    float bb = bih[a * 768 + 256 + col] + bhh[a * 768 + 256 + col];
#pragma unroll
    for (int mt = 0; mt < 2; ++mt)
#pragma unroll
      for (int r = 0; r < 4; ++r) {
        int row = mt * 16 + l4 * 4 + r;
        int flat = ((rowbase + row) << 3) + a;
        float ig = sigm(G[mt][nt][r] + 0.5f * (SX[mt][r] + SH[mt][r]) + bb);
        float hv = hin[(flat << 8) + col];   // f32, coalesced 4-line load
        float ng = T[mt][nt][r];
        out[QSIZE + (flat << 8) + col] = ng + ig * (hv - ng);
      }
  }
}

// ========================== K3: fc2 -> q (out) ==============================
__global__ __launch_bounds__(128) void k3_fc2(
    const float* __restrict__ b2, const unsigned short* __restrict__ ws,
    float* __restrict__ out) {
  __shared__ __align__(16) unsigned short HB[32 * 256];
  const int tid = threadIdx.x;
  const int a = blockIdx.x & 7;
  const int rowbase = (blockIdx.x >> 3) * 32;
  const int lane = tid & 63, w = tid >> 6;
  const int l16 = lane & 15, l4 = lane >> 4;

#pragma unroll
  for (int k = 0; k < 16; ++k) {
    int j = tid + k * 128;
    int r = j >> 6;
    int c4 = (j & 63) << 2;
    const float* sp = out + QSIZE + ((((rowbase + r) << 3) + a) << 8) + c4;
    float4 v = *(const float4*)sp;
    us4 hi = { f2bf(v.x), f2bf(v.y), f2bf(v.z), f2bf(v.w) };
    int idx = ((r << 8) + c4) ^ ((r & 7) << 3);
    *(us4*)(HB + idx) = hi;
  }
  __syncthreads();

  f32x4 qa[2];
  qa[0] = (f32x4){0.f, 0.f, 0.f, 0.f};
  qa[1] = (f32x4){0.f, 0.f, 0.f, 0.f};
#pragma unroll
  for (int ks = 0; ks < 8; ++ks) {
    int row = w * 16 + l16;
    int idx = ((row << 8) + ks * 32 + 8 * l4) ^ ((row & 7) << 3);
    s8 af = *(const s8*)(HB + idx);
#pragma unroll
    for (int nt = 0; nt < 2; ++nt) {
      s8 bw = *(const s8*)(ws + W2T_OFF + a * 8192 + nt * 4096 + ks * 512 + lane * 8);
      qa[nt] = __builtin_amdgcn_mfma_f32_16x16x32_bf16(af, bw, qa[nt], 0, 0, 0);
    }
  }
#pragma unroll
  for (int nt = 0; nt < 2; ++nt) {
    int col = nt * 16 + l16;
    if (col < 30) {
      float bb = b2[a * 30 + col];
#pragma unroll
      for (int r = 0; r < 4; ++r) {
        int row = w * 16 + l4 * 4 + r;
        out[(((rowbase + row) << 3) + a) * 30 + col] = fmaxf(qa[nt][r] + bb, 0.f);
      }
    }
  }
}

// ======= fallback (ws too small for XF/HF): fused kernel, fragment W ========
__global__ __launch_bounds__(256, 2) void fused_agent_rnn(
    const float* __restrict__ inp,  const float* __restrict__ hin,
    const float* __restrict__ b1,   const float* __restrict__ bih,
    const float* __restrict__ bhh,  const float* __restrict__ b2,
    const unsigned short* __restrict__ ws, float* __restrict__ out) {
  __shared__ __align__(16) unsigned short P0[32 * 256];
  __shared__ __align__(16) unsigned short P1[32 * 256];
  __shared__ float RSXP[8][32], RSHP[8][32];
  __shared__ float RSX[32], RSH[32];

  const int tid = threadIdx.x;
  const int a = blockIdx.x & 7;
  const int rowbase = (blockIdx.x >> 3) * 32;
  const int lane = tid & 63, w = tid >> 6;
  const int l16 = lane & 15, l4 = lane >> 4;
  const int n0 = w * 64;

  stage_split(P0, P1, inp, rowbase, a, tid);
  __syncthreads();
  {
    f32x4 XA[2][4];
#pragma unroll
    for (int mt = 0; mt < 2; ++mt)
#pragma unroll
      for (int nt = 0; nt < 4; ++nt) XA[mt][nt] = (f32x4){0.f, 0.f, 0.f, 0.f};
    mma64f(P0, ws + W1H_OFF + a * 65536, w * 4, lane, l16, l4, XA);
    mma64f(P1, ws + W1H_OFF + a * 65536, w * 4, lane, l16, l4, XA);
    mma64f(P0, ws + W1L_OFF + a * 65536, w * 4, lane, l16, l4, XA);
    __syncthreads();
#pragma unroll
    for (int nt = 0; nt < 4; ++nt) {
      int col = n0 + nt * 16 + l16;
      float bb = b1[a * 256 + col];
#pragma unroll
      for (int mt = 0; mt < 2; ++mt)
#pragma unroll
        for (int r = 0; r < 4; ++r) {
          float v = fmaxf(XA[mt][nt][r] + bb, 0.f);
          int row = mt * 16 + l4 * 4 + r;
          P0[((row << 8) + col) ^ ((row & 7) << 3)] = f2bf(v);
        }
    }
  }
  stage_single(P1, hin, rowbase, a, tid);
  __syncthreads();
  {
    int row = tid >> 3, qd = tid & 7;
    float sx = 0.f, sh = 0.f;
#pragma unroll
    for (int i = 0; i < 8; ++i) {
      int c = qd * 32 + i * 4;
      int idx = ((row << 8) + c) ^ ((row & 7) << 3);
      us4 vx = *(const us4*)(P0 + idx);
      us4 vh = *(const us4*)(P1 + idx);
      sx += bf2f(vx[0]) + bf2f(vx[1]) + bf2f(vx[2]) + bf2f(vx[3]);
      sh += bf2f(vh[0]) + bf2f(vh[1]) + bf2f(vh[2]) + bf2f(vh[3]);
    }
    RSXP[qd][row] = sx; RSHP[qd][row] = sh;
  }
  __syncthreads();
  if (tid < 32) {
    float sx = 0.f, sh = 0.f;
#pragma unroll
    for (int qd = 0; qd < 8; ++qd) { sx += RSXP[qd][tid]; sh += RSHP[qd][tid]; }
    RSX[tid] = sx; RSH[tid] = sh;
  }
  __syncthreads();

  const unsigned short* WihF = ws + WIH_OFF + a * 196608;
  const unsigned short* WhhF = ws + WHH_OFF + a * 196608;

  for (int nt = 0; nt < 4; ++nt) {
    const int col = n0 + nt * 16 + l16;
    const int cb = w * 4 + nt;               // gate-local col-block
    f32x4 R4[2], T4[2], G4[2];
#pragma unroll
    for (int mt = 0; mt < 2; ++mt) R4[mt] = (f32x4){0.f, 0.f, 0.f, 0.f};
    mma16f(P0, WihF, cb, lane, l16, l4, R4);
    mma16f(P1, WhhF, cb, lane, l16, l4, R4);
    {
      float bb = bih[a * 768 + col] + bhh[a * 768 + col];
#pragma unroll
      for (int mt = 0; mt < 2; ++mt)
#pragma unroll
        for (int r = 0; r < 4; ++r) {
          int row = mt * 16 + l4 * 4 + r;
          R4[mt][r] = sigm(R4[mt][r] + 0.5f * (RSX[row] + RSH[row]) + bb);
        }
    }
#pragma unroll
    for (int mt = 0; mt < 2; ++mt) T4[mt] = (f32x4){0.f, 0.f, 0.f, 0.f};
    mma16f(P1, WhhF, 32 + cb, lane, l16, l4, T4);
    {
      float bb = bhh[a * 768 + 512 + col];
#pragma unroll
      for (int mt = 0; mt < 2; ++mt)
#pragma unroll
        for (int r = 0; r < 4; ++r) {
          int row = mt * 16 + l4 * 4 + r;
          T4[mt][r] = R4[mt][r] * (T4[mt][r] + 0.5f * RSH[row] + bb);
        }
    }
#pragma unroll
    for (int mt = 0; mt < 2; ++mt) G4[mt] = (f32x4){0.f, 0.f, 0.f, 0.f};
    mma16f(P0, WihF, 32 + cb, lane, l16, l4, G4);
    {
      float bb = bih[a * 768 + 512 + col];
#pragma unroll
      for (int mt = 0; mt < 2; ++mt)
#pragma unroll
        for (int r = 0; r < 4; ++r) {
          int row = mt * 16 + l4 * 4 + r;
          T4[mt][r] = tanh_(G4[mt][r] + 0.5f * RSX[row] + bb + T4[mt][r]);
        }
    }
#pragma unroll
    for (int mt = 0; mt < 2; ++mt) G4[mt] = (f32x4){0.f, 0.f, 0.f, 0.f};
    mma16f(P0, WihF, 16 + cb, lane, l16, l4, G4);
    mma16f(P1, WhhF, 16 + cb, lane, l16, l4, G4);
    {
      float bb = bih[a * 768 + 256 + col] + bhh[a * 768 + 256 + col];
#pragma unroll
      for (int mt = 0; mt < 2; ++mt)
#pragma unroll
        for (int r = 0; r < 4; ++r) {
          int row = mt * 16 + l4 * 4 + r;
          float ig = sigm(G4[mt][r] + 0.5f * (RSX[row] + RSH[row]) + bb);
          float hv = bf2f(P1[((row << 8) + col) ^ ((row & 7) << 3)]);
          float ng = T4[mt][r];
          out[QSIZE + ((((rowbase + row) << 3) + a) << 8) + col]
              = ng + ig * (hv - ng);
        }
    }
  }
  __syncthreads();
  stage_single(P0, out + QSIZE, rowbase, a, tid);
  __syncthreads();
  if (w < 2) {
    f32x4 qa[2];
    qa[0] = (f32x4){0.f, 0.f, 0.f, 0.f};
    qa[1] = (f32x4){0.f, 0.f, 0.f, 0.f};
#pragma unroll
    for (int ks = 0; ks < 8; ++ks) {
      int row = w * 16 + l16;
      int idx = ((row << 8) + ks * 32 + 8 * l4) ^ ((row & 7) << 3);
      s8 af = *(const s8*)(P0 + idx);
#pragma unroll
      for (int nt = 0; nt < 2; ++nt) {
        s8 bw = *(const s8*)(ws + W2T_OFF + a * 8192 + nt * 4096 + ks * 512 + lane * 8);
        qa[nt] = __builtin_amdgcn_mfma_f32_16x16x32_bf16(af, bw, qa[nt], 0, 0, 0);
      }
    }
#pragma unroll
    for (int nt = 0; nt < 2; ++nt) {
      int col = nt * 16 + l16;
      if (col < 30) {
        float bb = b2[a * 30 + col];
#pragma unroll
        for (int r = 0; r < 4; ++r) {
          int row = w * 16 + l4 * 4 + r;
          out[(((rowbase + row) << 3) + a) * 30 + col] = fmaxf(qa[nt][r] + bb, 0.f);
        }
      }
    }
  }
}

extern "C" void kernel_launch(void* const* d_in, const int* in_sizes, int n_in,
                              void* d_out, int out_size, void* d_ws, size_t ws_size,
                              hipStream_t stream) {
  const float* inputs = (const float*)d_in[0];
  const float* hidden = (const float*)d_in[1];
  const float* fc1w   = (const float*)d_in[2];
  const float* fc1b   = (const float*)d_in[3];
  const float* rihw   = (const float*)d_in[4];
  const float* rihb   = (const float*)d_in[5];
  const float* rhhw   = (const float*)d_in[6];
  const float* rhhb   = (const float*)d_in[7];
  const float* fc2w   = (const float*)d_in[8];
  const float* fc2b   = (const float*)d_in[9];
  unsigned short* ws  = (unsigned short*)d_ws;
  float* out          = (float*)d_out;

  hipLaunchKernelGGL(prep_weights, dim3(3648), dim3(256), 0, stream,
                     fc1w, rihw, rhhw, fc2w, ws);

  if (ws_size >= WS_NEED_NEW) {
    hipLaunchKernelGGL(k1_fc1, dim3(1024), dim3(256), 0, stream,
                       inputs, hidden, fc1b, ws);
    hipLaunchKernelGGL(k2_gates_nw, dim3(2048), dim3(256), 0, stream,
                       hidden, rihb, rhhb, ws, out);
    hipLaunchKernelGGL(k3_fc2, dim3(1024), dim3(128), 0, stream, fc2b, ws, out);
  } else {
    hipLaunchKernelGGL(fused_agent_rnn, dim3(1024), dim3(256), 0, stream,
                       inputs, hidden, fc1b, rihb, rhhb, fc2b, ws, out);
  }
}

// Round 11
// 113.749 us; speedup vs baseline: 2.0841x; 1.1382x over previous
//
#include <hip/hip_runtime.h>

// ---------------------------------------------------------------------------
// LatentMixtureAllRNNAgent: per-agent fc1 -> GRU cell -> fc2 on MI355X.
// Round 11: k2 SINGLE-PASS. Round 10 (fragment layouts) cut k2 to 89us but
// it remains load-issue-bound: 192x1KB wave-loads/wave (A re-read each of 3
// phases). All four gate GEMMs (R,I and T=h@Whh_n, G=x@Wih_n are mutually
// independent) + MFMA rowsums now run in ONE ks-loop: 128 loads/wave.
// Accs R,I,T,G,SX,SH = 80 AGPR; ~110 VGPR < 128 cap of (256,2).
// Numerics identical to round 10 (absmax 1.0).
// ---------------------------------------------------------------------------

typedef __attribute__((ext_vector_type(4))) float f32x4;
typedef __attribute__((ext_vector_type(8))) short s8;     // 8 bf16 (4 VGPRs)
typedef __attribute__((ext_vector_type(4))) unsigned short us4;
typedef __attribute__((ext_vector_type(8))) unsigned short us8;

#define QSIZE   983040      /* 32768*30 */
#define W1H_OFF 0
#define W1L_OFF 524288
#define WIH_OFF 1048576
#define WHH_OFF 2621440
#define W2T_OFF 4194304
#define XB_OFF  4259840                 /* X fragments:   8a x 256rb x 4096 */
#define HB_OFF  12648448                /* h_in fragments: same */
#define WS_NEED_NEW 42074112ull

static __device__ __forceinline__ unsigned short f2bf(float f) {
  union { float f; unsigned u; } v; v.f = f;
  unsigned r = v.u + 0x7FFFu + ((v.u >> 16) & 1u);   // RNE
  return (unsigned short)(r >> 16);
}
static __device__ __forceinline__ float bf2f(unsigned short u) {
  union { unsigned u; float f; } v; v.u = ((unsigned)u) << 16;
  return v.f;
}
static __device__ __forceinline__ float sigm(float x) {
  return 1.0f / (1.0f + __expf(-x));
}
static __device__ __forceinline__ float tanh_(float x) {
  return 1.0f - 2.0f / (__expf(2.0f * x) + 1.0f);
}

// ---- prep: f32 [a][k][n] -> bf16 fragment layout [a][cb][ks][l4][l16][8] ---
__global__ void prep_weights(const float* __restrict__ fc1w,
                             const float* __restrict__ rihw,
                             const float* __restrict__ rhhw,
                             const float* __restrict__ fc2w,
                             unsigned short* __restrict__ ws) {
  int q = blockIdx.x * 256 + threadIdx.x;   // one us4 (4 k-values) per thread
  if (q < 131072) {                         // fc1: hi + lo, 8a x 16cb x 1024
    int a = q >> 14, rem = q & 16383;
    int cb = rem >> 10, s = rem & 1023;
    int ks = s >> 7, l4 = (s >> 5) & 3, l16 = (s >> 1) & 15, hf = s & 1;
    int n = cb * 16 + l16, k0 = ks * 32 + l4 * 8 + hf * 4;
    const float* sp = fc1w + a * 65536 + k0 * 256 + n;
    float v0 = sp[0], v1 = sp[256], v2 = sp[512], v3 = sp[768];
    us4 hi = { f2bf(v0), f2bf(v1), f2bf(v2), f2bf(v3) };
    us4 lo = { f2bf(v0 - bf2f(hi[0])), f2bf(v1 - bf2f(hi[1])),
               f2bf(v2 - bf2f(hi[2])), f2bf(v3 - bf2f(hi[3])) };
    int o = a * 65536 + cb * 4096 + ks * 512 + l4 * 128 + l16 * 8 + hf * 4;
    *(us4*)(ws + W1H_OFF + o) = hi;
    *(us4*)(ws + W1L_OFF + o) = lo;
  } else if (q < 524288) {                  // rnn_ih centered: 8a x 48cb
    int t = q - 131072;
    int a = t / 49152, rem = t % 49152;
    int cb = rem >> 10, s = rem & 1023;
    int ks = s >> 7, l4 = (s >> 5) & 3, l16 = (s >> 1) & 15, hf = s & 1;
    int n = cb * 16 + l16, k0 = ks * 32 + l4 * 8 + hf * 4;
    const float* sp = rihw + a * 196608 + k0 * 768 + n;
    us4 v = { f2bf(sp[0] - 0.5f), f2bf(sp[768] - 0.5f),
              f2bf(sp[1536] - 0.5f), f2bf(sp[2304] - 0.5f) };
    *(us4*)(ws + WIH_OFF + a * 196608 + cb * 4096 + ks * 512 + l4 * 128
            + l16 * 8 + hf * 4) = v;
  } else if (q < 917504) {                  // rnn_hh centered
    int t = q - 524288;
    int a = t / 49152, rem = t % 49152;
    int cb = rem >> 10, s = rem & 1023;
    int ks = s >> 7, l4 = (s >> 5) & 3, l16 = (s >> 1) & 15, hf = s & 1;
    int n = cb * 16 + l16, k0 = ks * 32 + l4 * 8 + hf * 4;
    const float* sp = rhhw + a * 196608 + k0 * 768 + n;
    us4 v = { f2bf(sp[0] - 0.5f), f2bf(sp[768] - 0.5f),
              f2bf(sp[1536] - 0.5f), f2bf(sp[2304] - 0.5f) };
    *(us4*)(ws + WHH_OFF + a * 196608 + cb * 4096 + ks * 512 + l4 * 128
            + l16 * 8 + hf * 4) = v;
  } else if (q < 933888) {                  // fc2: 8a x 2cb, pad n>=30 -> 0
    int t = q - 917504;
    int a = t >> 11, rem = t & 2047;
    int cb = rem >> 10, s = rem & 1023;
    int ks = s >> 7, l4 = (s >> 5) & 3, l16 = (s >> 1) & 15, hf = s & 1;
    int n = cb * 16 + l16, k0 = ks * 32 + l4 * 8 + hf * 4;
    us4 v = { 0, 0, 0, 0 };
    if (n < 30) {
      const float* sp = fc2w + a * 7680 + k0 * 30 + n;
      v = (us4){ f2bf(sp[0]), f2bf(sp[30]), f2bf(sp[60]), f2bf(sp[90]) };
    }
    *(us4*)(ws + W2T_OFF + a * 8192 + cb * 4096 + ks * 512 + l4 * 128
            + l16 * 8 + hf * 4) = v;
  }
}

// ------- stage 32x256 f32 tile -> split bf16 (hi p0, lo p1), 256 thr --------
static __device__ __forceinline__ void stage_split(unsigned short* p0,
                                                   unsigned short* p1,
                                                   const float* __restrict__ src,
                                                   int rowbase, int a, int tid) {
#pragma unroll
  for (int k = 0; k < 8; ++k) {
    int j = tid + k * 256;
    int r = j >> 6;
    int c4 = (j & 63) << 2;
    const float* p = src + ((((rowbase + r) << 3) + a) << 8) + c4;
    float4 v = *(const float4*)p;
    us4 hi = { f2bf(v.x), f2bf(v.y), f2bf(v.z), f2bf(v.w) };
    us4 lo = { f2bf(v.x - bf2f(hi[0])), f2bf(v.y - bf2f(hi[1])),
               f2bf(v.z - bf2f(hi[2])), f2bf(v.w - bf2f(hi[3])) };
    int idx = ((r << 8) + c4) ^ ((r & 7) << 3);   // XOR swizzle (16B blocks)
    *(us4*)(p0 + idx) = hi;
    *(us4*)(p1 + idx) = lo;
  }
}

// ------------- stage 32x256 f32 tile -> single bf16 plane, 256 thr ----------
static __device__ __forceinline__ void stage_single(unsigned short* p,
                                                    const float* __restrict__ src,
                                                    int rowbase, int a, int tid) {
#pragma unroll
  for (int k = 0; k < 8; ++k) {
    int j = tid + k * 256;
    int r = j >> 6;
    int c4 = (j & 63) << 2;
    const float* sp = src + ((((rowbase + r) << 3) + a) << 8) + c4;
    float4 v = *(const float4*)sp;
    us4 hi = { f2bf(v.x), f2bf(v.y), f2bf(v.z), f2bf(v.w) };
    int idx = ((r << 8) + c4) ^ ((r & 7) << 3);
    *(us4*)(p + idx) = hi;
  }
}

// ---- 32x64 GEMM over K=256, B from fragment layout (contiguous loads) ------
static __device__ __forceinline__ void mma64f(const unsigned short* lds,
                                              const unsigned short* __restrict__ wf,
                                              int cb0, int lane, int l16, int l4,
                                              f32x4 (&acc)[2][4]) {
#pragma unroll
  for (int ks = 0; ks < 8; ++ks) {
    s8 af[2], bw[4];
#pragma unroll
    for (int mt = 0; mt < 2; ++mt) {
      int row = mt * 16 + l16;
      int idx = ((row << 8) + ks * 32 + 8 * l4) ^ ((row & 7) << 3);
      af[mt] = *(const s8*)(lds + idx);
    }
#pragma unroll
    for (int nt = 0; nt < 4; ++nt)
      bw[nt] = *(const s8*)(wf + (cb0 + nt) * 4096 + ks * 512 + lane * 8);
#pragma unroll
    for (int mt = 0; mt < 2; ++mt)
#pragma unroll
      for (int nt = 0; nt < 4; ++nt)
        acc[mt][nt] = __builtin_amdgcn_mfma_f32_16x16x32_bf16(
            af[mt], bw[nt], acc[mt][nt], 0, 0, 0);
  }
}

// ---- 32x16 GEMM over K=256, fragment B (fallback kernel) -------------------
static __device__ __forceinline__ void mma16f(const unsigned short* lds,
                                              const unsigned short* __restrict__ wf,
                                              int cb, int lane, int l16, int l4,
                                              f32x4 (&acc)[2]) {
#pragma unroll
  for (int ks = 0; ks < 8; ++ks) {
    s8 bw = *(const s8*)(wf + cb * 4096 + ks * 512 + lane * 8);
#pragma unroll
    for (int mt = 0; mt < 2; ++mt) {
      int row = mt * 16 + l16;
      int idx = ((row << 8) + ks * 32 + 8 * l4) ^ ((row & 7) << 3);
      s8 af = *(const s8*)(lds + idx);
      acc[mt] = __builtin_amdgcn_mfma_f32_16x16x32_bf16(af, bw, acc[mt], 0, 0, 0);
    }
  }
}

// ====== K1: fc1 -> X fragments; h_in -> bf16 fragments (LDS bounce) =========
__global__ __launch_bounds__(256, 2) void k1_fc1(
    const float* __restrict__ inp, const float* __restrict__ hin,
    const float* __restrict__ b1, unsigned short* __restrict__ ws) {
  __shared__ __align__(16) unsigned short P0[32 * 256];
  __shared__ __align__(16) unsigned short P1[32 * 256];
  const int tid = threadIdx.x;
  const int a = blockIdx.x & 7;
  const int rt = blockIdx.x >> 3;
  const int rowbase = rt * 32;
  const int lane = tid & 63, w = tid >> 6;
  const int l16 = lane & 15, l4 = lane >> 4;
  const int n0 = w * 64;

  stage_split(P0, P1, inp, rowbase, a, tid);
  __syncthreads();

  f32x4 XA[2][4];
#pragma unroll
  for (int mt = 0; mt < 2; ++mt)
#pragma unroll
    for (int nt = 0; nt < 4; ++nt) XA[mt][nt] = (f32x4){0.f, 0.f, 0.f, 0.f};
  mma64f(P0, ws + W1H_OFF + a * 65536, w * 4, lane, l16, l4, XA);
  mma64f(P1, ws + W1H_OFF + a * 65536, w * 4, lane, l16, l4, XA);
  mma64f(P0, ws + W1L_OFF + a * 65536, w * 4, lane, l16, l4, XA);
  __syncthreads();                           // all LDS reads done

  // write x bf16 -> P0 (swizzled); stage h_in bf16 -> P1 (swizzled)
#pragma unroll
  for (int nt = 0; nt < 4; ++nt) {
    int col = n0 + nt * 16 + l16;
    float bb = b1[a * 256 + col];
#pragma unroll
    for (int mt = 0; mt < 2; ++mt)
#pragma unroll
      for (int r = 0; r < 4; ++r) {
        float v = fmaxf(XA[mt][nt][r] + bb, 0.f);
        int row = mt * 16 + l4 * 4 + r;
        P0[((row << 8) + col) ^ ((row & 7) << 3)] = f2bf(v);
      }
  }
  stage_single(P1, hin, rowbase, a, tid);
  __syncthreads();

  // fragment-dump: P0 -> XF, P1 -> HF (contiguous us8 wave stores)
  const int rbg = (a << 8) + rt * 2;
#pragma unroll
  for (int i = 0; i < 4; ++i) {
    int c = tid + i * 256;                   // 0..1023 us8 chunks
    int rb = c >> 9, s = c & 511;            // s = ks*64 + l4*16 + l16
    int row = rb * 16 + (s & 15);
    int col = ((s >> 6) << 5) + (((s >> 4) & 3) << 3);
    int idx = ((row << 8) + col) ^ ((row & 7) << 3);
    *(us8*)(ws + XB_OFF + (rbg + rb) * 4096 + s * 8) = *(const us8*)(P0 + idx);
    *(us8*)(ws + HB_OFF + (rbg + rb) * 4096 + s * 8) = *(const us8*)(P1 + idx);
  }
}

// ====== K2: SINGLE-PASS — all 4 gate GEMMs + rowsums in one ks loop =========
__global__ __launch_bounds__(256, 2) void k2_gates_nw(
    const float* __restrict__ hin, const float* __restrict__ bih,
    const float* __restrict__ bhh, const unsigned short* __restrict__ ws,
    float* __restrict__ out) {
  const int lane = threadIdx.x & 63;
  const int w    = threadIdx.x >> 6;
  const int bid  = blockIdx.x;
  const int a    = bid & 7;                 // agent == XCD
  const int g    = bid >> 3;
  const int rt   = g >> 1;                  // row-tile (slow)
  const int cs   = (g & 1) * 4 + w;         // col-slice 0..7
  const int rowbase = rt * 32;
  const int n0   = cs * 32;
  const int l16  = lane & 15, l4 = lane >> 4;

  const unsigned short* XF = ws + XB_OFF + ((a << 8) + rt * 2) * 4096 + lane * 8;
  const unsigned short* HF = ws + HB_OFF + ((a << 8) + rt * 2) * 4096 + lane * 8;
  const unsigned short* WihR = ws + WIH_OFF + a * 196608 + (cs * 2) * 4096 + lane * 8;
  const unsigned short* WhhR = ws + WHH_OFF + a * 196608 + (cs * 2) * 4096 + lane * 8;

  s8 ones;
#pragma unroll
  for (int i = 0; i < 8; ++i) ones[i] = (short)0x3F80;

  f32x4 R[2][2], I[2][2], T[2][2], G[2][2], SX[2], SH[2];
#pragma unroll
  for (int mt = 0; mt < 2; ++mt) {
    SX[mt] = (f32x4){0.f, 0.f, 0.f, 0.f};
    SH[mt] = (f32x4){0.f, 0.f, 0.f, 0.f};
#pragma unroll
    for (int nt = 0; nt < 2; ++nt) {
      R[mt][nt] = (f32x4){0.f, 0.f, 0.f, 0.f};
      I[mt][nt] = (f32x4){0.f, 0.f, 0.f, 0.f};
      T[mt][nt] = (f32x4){0.f, 0.f, 0.f, 0.f};
      G[mt][nt] = (f32x4){0.f, 0.f, 0.f, 0.f};
    }
  }

  // ---- single pass: 16 loads, 28 MFMA per ks ----
#pragma unroll 2
  for (int ks = 0; ks < 8; ++ks) {
    const int ko = ks * 512;
    s8 ax[2], ah[2];
#pragma unroll
    for (int mt = 0; mt < 2; ++mt) {
      ax[mt] = *(const s8*)(XF + mt * 4096 + ko);
      ah[mt] = *(const s8*)(HF + mt * 4096 + ko);
    }
    s8 bxr[2], bhr[2], bxi[2], bhi[2], bxn[2], bhn[2];
#pragma unroll
    for (int nt = 0; nt < 2; ++nt) {
      bxr[nt] = *(const s8*)(WihR + nt * 4096 + ko);
      bhr[nt] = *(const s8*)(WhhR + nt * 4096 + ko);
      bxi[nt] = *(const s8*)(WihR + (16 + nt) * 4096 + ko);
      bhi[nt] = *(const s8*)(WhhR + (16 + nt) * 4096 + ko);
      bxn[nt] = *(const s8*)(WihR + (32 + nt) * 4096 + ko);
      bhn[nt] = *(const s8*)(WhhR + (32 + nt) * 4096 + ko);
    }
#pragma unroll
    for (int mt = 0; mt < 2; ++mt) {
      SX[mt] = __builtin_amdgcn_mfma_f32_16x16x32_bf16(ax[mt], ones, SX[mt], 0, 0, 0);
      SH[mt] = __builtin_amdgcn_mfma_f32_16x16x32_bf16(ah[mt], ones, SH[mt], 0, 0, 0);
#pragma unroll
      for (int nt = 0; nt < 2; ++nt) {
        R[mt][nt] = __builtin_amdgcn_mfma_f32_16x16x32_bf16(ax[mt], bxr[nt], R[mt][nt], 0, 0, 0);
        R[mt][nt] = __builtin_amdgcn_mfma_f32_16x16x32_bf16(ah[mt], bhr[nt], R[mt][nt], 0, 0, 0);
        I[mt][nt] = __builtin_amdgcn_mfma_f32_16x16x32_bf16(ax[mt], bxi[nt], I[mt][nt], 0, 0, 0);
        I[mt][nt] = __builtin_amdgcn_mfma_f32_16x16x32_bf16(ah[mt], bhi[nt], I[mt][nt], 0, 0, 0);
        G[mt][nt] = __builtin_amdgcn_mfma_f32_16x16x32_bf16(ax[mt], bxn[nt], G[mt][nt], 0, 0, 0);
        T[mt][nt] = __builtin_amdgcn_mfma_f32_16x16x32_bf16(ah[mt], bhn[nt], T[mt][nt], 0, 0, 0);
      }
    }
  }

  // ---- epilogue: gates, combine, store h ----
#pragma unroll
  for (int nt = 0; nt < 2; ++nt) {
    int col = n0 + nt * 16 + l16;
    float br = bih[a * 768 + col] + bhh[a * 768 + col];
    float bi = bih[a * 768 + 256 + col] + bhh[a * 768 + 256 + col];
    float bnh = bhh[a * 768 + 512 + col];
    float bni = bih[a * 768 + 512 + col];
#pragma unroll
    for (int mt = 0; mt < 2; ++mt)
#pragma unroll
      for (int r = 0; r < 4; ++r) {
        float rsx = SX[mt][r], rsh = SH[mt][r];
        float rg = sigm(R[mt][nt][r] + 0.5f * (rsx + rsh) + br);
        float t  = rg * (T[mt][nt][r] + 0.5f * rsh + bnh);
        float ng = tanh_(G[mt][nt][r] + 0.5f * rsx + bni + t);
        float ig = sigm(I[mt][nt][r] + 0.5f * (rsx + rsh) + bi);
        int row = mt * 16 + l4 * 4 + r;
        int flat = ((rowbase + row) << 3) + a;
        float hv = hin[(flat << 8) + col];
        out[QSIZE + (flat << 8) + col] = ng + ig * (hv - ng);
      }
  }
}

// ========================== K3: fc2 -> q (out) ==============================
__global__ __launch_bounds__(128) void k3_fc2(
    const float* __restrict__ b2, const unsigned short* __restrict__ ws,
    float* __restrict__ out) {
  __shared__ __align__(16) unsigned short HB[32 * 256];
  const int tid = threadIdx.x;
  const int a = blockIdx.x & 7;
  const int rowbase = (blockIdx.x >> 3) * 32;
  const int lane = tid & 63, w = tid >> 6;
  const int l16 = lane & 15, l4 = lane >> 4;

#pragma unroll
  for (int k = 0; k < 16; ++k) {
    int j = tid + k * 128;
    int r = j >> 6;
    int c4 = (j & 63) << 2;
    const float* sp = out + QSIZE + ((((rowbase + r) << 3) + a) << 8) + c4;
    float4 v = *(const float4*)sp;
    us4 hi = { f2bf(v.x), f2bf(v.y), f2bf(v.z), f2bf(v.w) };
    int idx = ((r << 8) + c4) ^ ((r & 7) << 3);
    *(us4*)(HB + idx) = hi;
  }
  __syncthreads();

  f32x4 qa[2];
  qa[0] = (f32x4){0.f, 0.f, 0.f, 0.f};
  qa[1] = (f32x4){0.f, 0.f, 0.f, 0.f};
#pragma unroll
  for (int ks = 0; ks < 8; ++ks) {
    int row = w * 16 + l16;
    int idx = ((row << 8) + ks * 32 + 8 * l4) ^ ((row & 7) << 3);
    s8 af = *(const s8*)(HB + idx);
#pragma unroll
    for (int nt = 0; nt < 2; ++nt) {
      s8 bw = *(const s8*)(ws + W2T_OFF + a * 8192 + nt * 4096 + ks * 512 + lane * 8);
      qa[nt] = __builtin_amdgcn_mfma_f32_16x16x32_bf16(af, bw, qa[nt], 0, 0, 0);
    }
  }
#pragma unroll
  for (int nt = 0; nt < 2; ++nt) {
    int col = nt * 16 + l16;
    if (col < 30) {
      float bb = b2[a * 30 + col];
#pragma unroll
      for (int r = 0; r < 4; ++r) {
        int row = w * 16 + l4 * 4 + r;
        out[(((rowbase + row) << 3) + a) * 30 + col] = fmaxf(qa[nt][r] + bb, 0.f);
      }
    }
  }
}

// ======= fallback (ws too small for XF/HF): fused kernel, fragment W ========
__global__ __launch_bounds__(256, 2) void fused_agent_rnn(
    const float* __restrict__ inp,  const float* __restrict__ hin,
    const float* __restrict__ b1,   const float* __restrict__ bih,
    const float* __restrict__ bhh,  const float* __restrict__ b2,
    const unsigned short* __restrict__ ws, float* __restrict__ out) {
  __shared__ __align__(16) unsigned short P0[32 * 256];
  __shared__ __align__(16) unsigned short P1[32 * 256];
  __shared__ float RSXP[8][32], RSHP[8][32];
  __shared__ float RSX[32], RSH[32];

  const int tid = threadIdx.x;
  const int a = blockIdx.x & 7;
  const int rowbase = (blockIdx.x >> 3) * 32;
  const int lane = tid & 63, w = tid >> 6;
  const int l16 = lane & 15, l4 = lane >> 4;
  const int n0 = w * 64;

  stage_split(P0, P1, inp, rowbase, a, tid);
  __syncthreads();
  {
    f32x4 XA[2][4];
#pragma unroll
    for (int mt = 0; mt < 2; ++mt)
#pragma unroll
      for (int nt = 0; nt < 4; ++nt) XA[mt][nt] = (f32x4){0.f, 0.f, 0.f, 0.f};
    mma64f(P0, ws + W1H_OFF + a * 65536, w * 4, lane, l16, l4, XA);
    mma64f(P1, ws + W1H_OFF + a * 65536, w * 4, lane, l16, l4, XA);
    mma64f(P0, ws + W1L_OFF + a * 65536, w * 4, lane, l16, l4, XA);
    __syncthreads();
#pragma unroll
    for (int nt = 0; nt < 4; ++nt) {
      int col = n0 + nt * 16 + l16;
      float bb = b1[a * 256 + col];
#pragma unroll
      for (int mt = 0; mt < 2; ++mt)
#pragma unroll
        for (int r = 0; r < 4; ++r) {
          float v = fmaxf(XA[mt][nt][r] + bb, 0.f);
          int row = mt * 16 + l4 * 4 + r;
          P0[((row << 8) + col) ^ ((row & 7) << 3)] = f2bf(v);
        }
    }
  }
  stage_single(P1, hin, rowbase, a, tid);
  __syncthreads();
  {
    int row = tid >> 3, qd = tid & 7;
    float sx = 0.f, sh = 0.f;
#pragma unroll
    for (int i = 0; i < 8; ++i) {
      int c = qd * 32 + i * 4;
      int idx = ((row << 8) + c) ^ ((row & 7) << 3);
      us4 vx = *(const us4*)(P0 + idx);
      us4 vh = *(const us4*)(P1 + idx);
      sx += bf2f(vx[0]) + bf2f(vx[1]) + bf2f(vx[2]) + bf2f(vx[3]);
      sh += bf2f(vh[0]) + bf2f(vh[1]) + bf2f(vh[2]) + bf2f(vh[3]);
    }
    RSXP[qd][row] = sx; RSHP[qd][row] = sh;
  }
  __syncthreads();
  if (tid < 32) {
    float sx = 0.f, sh = 0.f;
#pragma unroll
    for (int qd = 0; qd < 8; ++qd) { sx += RSXP[qd][tid]; sh += RSHP[qd][tid]; }
    RSX[tid] = sx; RSH[tid] = sh;
  }
  __syncthreads();

  const unsigned short* WihF = ws + WIH_OFF + a * 196608;
  const unsigned short* WhhF = ws + WHH_OFF + a * 196608;

  for (int nt = 0; nt < 4; ++nt) {
    const int col = n0 + nt * 16 + l16;
    const int cb = w * 4 + nt;               // gate-local col-block
    f32x4 R4[2], T4[2], G4[2];
#pragma unroll
    for (int mt = 0; mt < 2; ++mt) R4[mt] = (f32x4){0.f, 0.f, 0.f, 0.f};
    mma16f(P0, WihF, cb, lane, l16, l4, R4);
    mma16f(P1, WhhF, cb, lane, l16, l4, R4);
    {
      float bb = bih[a * 768 + col] + bhh[a * 768 + col];
#pragma unroll
      for (int mt = 0; mt < 2; ++mt)
#pragma unroll
        for (int r = 0; r < 4; ++r) {
          int row = mt * 16 + l4 * 4 + r;
          R4[mt][r] = sigm(R4[mt][r] + 0.5f * (RSX[row] + RSH[row]) + bb);
        }
    }
#pragma unroll
    for (int mt = 0; mt < 2; ++mt) T4[mt] = (f32x4){0.f, 0.f, 0.f, 0.f};
    mma16f(P1, WhhF, 32 + cb, lane, l16, l4, T4);
    {
      float bb = bhh[a * 768 + 512 + col];
#pragma unroll
      for (int mt = 0; mt < 2; ++mt)
#pragma unroll
        for (int r = 0; r < 4; ++r) {
          int row = mt * 16 + l4 * 4 + r;
          T4[mt][r] = R4[mt][r] * (T4[mt][r] + 0.5f * RSH[row] + bb);
        }
    }
#pragma unroll
    for (int mt = 0; mt < 2; ++mt) G4[mt] = (f32x4){0.f, 0.f, 0.f, 0.f};
    mma16f(P0, WihF, 32 + cb, lane, l16, l4, G4);
    {
      float bb = bih[a * 768 + 512 + col];
#pragma unroll
      for (int mt = 0; mt < 2; ++mt)
#pragma unroll
        for (int r = 0; r < 4; ++r) {
          int row = mt * 16 + l4 * 4 + r;
          T4[mt][r] = tanh_(G4[mt][r] + 0.5f * RSX[row] + bb + T4[mt][r]);
        }
    }
#pragma unroll
    for (int mt = 0; mt < 2; ++mt) G4[mt] = (f32x4){0.f, 0.f, 0.f, 0.f};
    mma16f(P0, WihF, 16 + cb, lane, l16, l4, G4);
    mma16f(P1, WhhF, 16 + cb, lane, l16, l4, G4);
    {
      float bb = bih[a * 768 + 256 + col] + bhh[a * 768 + 256 + col];
#pragma unroll
      for (int mt = 0; mt < 2; ++mt)
#pragma unroll
        for (int r = 0; r < 4; ++r) {
          int row = mt * 16 + l4 * 4 + r;
          float ig = sigm(G4[mt][r] + 0.5f * (RSX[row] + RSH[row]) + bb);
          float hv = bf2f(P1[((row << 8) + col) ^ ((row & 7) << 3)]);
          float ng = T4[mt][r];
          out[QSIZE + ((((rowbase + row) << 3) + a) << 8) + col]
              = ng + ig * (hv - ng);
        }
    }
  }
  __syncthreads();
  stage_single(P0, out + QSIZE, rowbase, a, tid);
  __syncthreads();
  if (w < 2) {
    f32x4 qa[2];
    qa[0] = (f32x4){0.f, 0.f, 0.f, 0.f};
    qa[1] = (f32x4){0.f, 0.f, 0.f, 0.f};
#pragma unroll
    for (int ks = 0; ks < 8; ++ks) {
      int row = w * 16 + l16;
      int idx = ((row << 8) + ks * 32 + 8 * l4) ^ ((row & 7) << 3);
      s8 af = *(const s8*)(P0 + idx);
#pragma unroll
      for (int nt = 0; nt < 2; ++nt) {
        s8 bw = *(const s8*)(ws + W2T_OFF + a * 8192 + nt * 4096 + ks * 512 + lane * 8);
        qa[nt] = __builtin_amdgcn_mfma_f32_16x16x32_bf16(af, bw, qa[nt], 0, 0, 0);
      }
    }
#pragma unroll
    for (int nt = 0; nt < 2; ++nt) {
      int col = nt * 16 + l16;
      if (col < 30) {
        float bb = b2[a * 30 + col];
#pragma unroll
        for (int r = 0; r < 4; ++r) {
          int row = w * 16 + l4 * 4 + r;
          out[(((rowbase + row) << 3) + a) * 30 + col] = fmaxf(qa[nt][r] + bb, 0.f);
        }
      }
    }
  }
}

extern "C" void kernel_launch(void* const* d_in, const int* in_sizes, int n_in,
                              void* d_out, int out_size, void* d_ws, size_t ws_size,
                              hipStream_t stream) {
  const float* inputs = (const float*)d_in[0];
  const float* hidden = (const float*)d_in[1];
  const float* fc1w   = (const float*)d_in[2];
  const float* fc1b   = (const float*)d_in[3];
  const float* rihw   = (const float*)d_in[4];
  const float* rihb   = (const float*)d_in[5];
  const float* rhhw   = (const float*)d_in[6];
  const float* rhhb   = (const float*)d_in[7];
  const float* fc2w   = (const float*)d_in[8];
  const float* fc2b   = (const float*)d_in[9];
  unsigned short* ws  = (unsigned short*)d_ws;
  float* out          = (float*)d_out;

  hipLaunchKernelGGL(prep_weights, dim3(3648), dim3(256), 0, stream,
                     fc1w, rihw, rhhw, fc2w, ws);

  if (ws_size >= WS_NEED_NEW) {
    hipLaunchKernelGGL(k1_fc1, dim3(1024), dim3(256), 0, stream,
                       inputs, hidden, fc1b, ws);
    hipLaunchKernelGGL(k2_gates_nw, dim3(2048), dim3(256), 0, stream,
                       hidden, rihb, rhhb, ws, out);
    hipLaunchKernelGGL(k3_fc2, dim3(1024), dim3(128), 0, stream, fc2b, ws, out);
  } else {
    hipLaunchKernelGGL(fused_agent_rnn, dim3(1024), dim3(256), 0, stream,
                       inputs, hidden, fc1b, rihb, rhhb, fc2b, ws, out);
  }
}